// Round 2
// baseline (1420.415 us; speedup 1.0000x reference)
//
#include <hip/hip_runtime.h>
#include <hip/hip_bf16.h>

// ---- problem constants ----
#define B_SZ   2
#define L_SZ   2048
#define DM     2048
#define DS     128
#define DCV    4
#define HD     64
#define CH     256
#define DI     4096
#define NH     64
#define DIP    8512
#define CDIM   4352
#define NP     8576      // DIP padded to 67*128
#define MROWS  4096      // B_SZ*L_SZ
#define NCK    8         // L_SZ/CH

typedef __attribute__((ext_vector_type(8))) short bf16x8;
typedef __attribute__((ext_vector_type(4))) float f32x4;
typedef unsigned short u16;

__device__ __forceinline__ u16 f2bf(float f) {
    union { float f; unsigned u; } c; c.f = f;
    unsigned r = c.u + 0x7fffu + ((c.u >> 16) & 1u);
    return (u16)(r >> 16);
}
__device__ __forceinline__ float bf2f(u16 b) {
    union { unsigned u; float f; } c; c.u = ((unsigned)b) << 16; return c.f;
}

// ---- 0a: u f32 -> bf16 ----
__global__ void cvt_u_kernel(const float* __restrict__ u, u16* __restrict__ ub) {
    int i = blockIdx.x * 256 + threadIdx.x;       // one float4 per thread
    float4 v = ((const float4*)u)[i];
    ushort4 o;
    o.x = f2bf(v.x); o.y = f2bf(v.y); o.z = f2bf(v.z); o.w = f2bf(v.w);
    ((ushort4*)ub)[i] = o;
}

// ---- 0b: w_in (K=2048 x DIP) f32 -> w_inT (NP x K) bf16, zero-pad rows >= DIP ----
__global__ void transpose_w_kernel(const float* __restrict__ w, u16* __restrict__ wt) {
    __shared__ float tile[32][33];
    int n0 = blockIdx.x * 32, k0 = blockIdx.y * 32;
    int tx = threadIdx.x & 31, ty = threadIdx.x >> 5;   // ty 0..7
    for (int j = 0; j < 32; j += 8) {
        int k = k0 + ty + j, n = n0 + tx;
        tile[ty + j][tx] = (n < DIP) ? w[(size_t)k * DIP + n] : 0.f;
    }
    __syncthreads();
    for (int j = 0; j < 32; j += 8) {
        int n = n0 + ty + j, k = k0 + tx;
        wt[(size_t)n * DM + k] = f2bf(tile[tx][ty + j]);
    }
}

// ---- 1: GEMM zxbcdt = u @ w_in  -> bf16 [MROWS][NP] ----
__global__ __launch_bounds__(256) void gemm_kernel(const u16* __restrict__ A,
                                                   const u16* __restrict__ Bt,
                                                   u16* __restrict__ C) {
    __shared__ u16 As[128 * 72];
    __shared__ u16 Bs[128 * 72];
    const int m0 = blockIdx.y * 128, n0 = blockIdx.x * 128;
    const int tid = threadIdx.x;
    const int lane = tid & 63, wid = tid >> 6;
    const int wm = (wid >> 1) * 64, wn = (wid & 1) * 64;
    const int quad = lane >> 4, lm = lane & 15;
    const int srow = tid >> 3;          // 0..31
    const int scol = (tid & 7) * 8;     // 0..56
    f32x4 acc[4][4] = {};
    for (int k0 = 0; k0 < DM; k0 += 64) {
        int4 av[4], bv[4];
        for (int p = 0; p < 4; p++) {
            av[p] = *(const int4*)(A  + (size_t)(m0 + srow + 32 * p) * DM + k0 + scol);
            bv[p] = *(const int4*)(Bt + (size_t)(n0 + srow + 32 * p) * DM + k0 + scol);
        }
        __syncthreads();
        for (int p = 0; p < 4; p++) {
            *(int4*)(As + (srow + 32 * p) * 72 + scol) = av[p];
            *(int4*)(Bs + (srow + 32 * p) * 72 + scol) = bv[p];
        }
        __syncthreads();
        for (int ks = 0; ks < 64; ks += 32) {
            bf16x8 af[4], bfr[4];
            for (int i = 0; i < 4; i++) af[i]  = *(const bf16x8*)(As + (wm + i * 16 + lm) * 72 + ks + quad * 8);
            for (int j = 0; j < 4; j++) bfr[j] = *(const bf16x8*)(Bs + (wn + j * 16 + lm) * 72 + ks + quad * 8);
            for (int i = 0; i < 4; i++)
                for (int j = 0; j < 4; j++)
                    acc[i][j] = __builtin_amdgcn_mfma_f32_16x16x32_bf16(af[i], bfr[j], acc[i][j], 0, 0, 0);
        }
    }
    for (int i = 0; i < 4; i++)
        for (int j = 0; j < 4; j++)
            for (int r = 0; r < 4; r++) {
                int gm = m0 + wm + i * 16 + quad * 4 + r;
                int gn = n0 + wn + j * 16 + lm;
                C[(size_t)gm * NP + gn] = f2bf(acc[i][j][r]);
            }
}

// ---- 2: causal depthwise conv(4) + SiLU ----
__global__ void conv_silu_kernel(const u16* __restrict__ zx, const float* __restrict__ cw,
                                 const float* __restrict__ cb, u16* __restrict__ xbc) {
    int c = blockIdx.x * 256 + threadIdx.x;   // < CDIM (17*256)
    int row = blockIdx.y;                     // 0..4095
    int l = row & (L_SZ - 1);
    float acc = cb[c];
    for (int k = 0; k < DCV; k++) {
        int ls = l - 3 + k;
        if (ls >= 0) acc += bf2f(zx[(size_t)(row - 3 + k) * NP + DI + c]) * cw[c * DCV + k];
    }
    float s = acc / (1.f + expf(-acc));
    xbc[(size_t)row * CDIM + c] = f2bf(s);
}

// ---- 3: dt = softplus(raw+bias), per-chunk cumsum of dA ----
__global__ void dt_scan_kernel(const u16* __restrict__ zx, const float* __restrict__ dt_bias,
                               const float* __restrict__ A_log, float* __restrict__ dtb,
                               float* __restrict__ acs) {
    int bid = blockIdx.x;                 // 1024 = b*512 + c*64 + h
    int h = bid & 63, c = (bid >> 6) & 7, b = bid >> 9;
    int t = threadIdx.x;
    int row = b * L_SZ + c * CH + t;
    float raw = bf2f(zx[(size_t)row * NP + (DI + CDIM) + h]) + dt_bias[h];
    float dtv = (raw > 20.f) ? raw : log1pf(expf(raw));
    float dA = dtv * (-expf(A_log[h]));
    dtb[row * NH + h] = dtv;
    __shared__ float sc[256];
    sc[t] = dA;
    for (int off = 1; off < 256; off <<= 1) {
        __syncthreads();
        float v = (t >= off) ? sc[t - off] : 0.f;
        __syncthreads();
        sc[t] += v;
    }
    acs[((size_t)((b * NH + h) * NCK + c)) * CH + t] = sc[t];
}

// ---- 4: G[t,s] = sum_n Cm[t,n]*Bm[s,n] per (b,c) ----
__global__ void g_kernel(const u16* __restrict__ xbc, float* __restrict__ G) {
    int blk = blockIdx.x;         // 256 = bc*16 + tile
    int bc = blk >> 4;
    int tile = blk & 15;
    int tb0 = (tile >> 2) * 64, sb0 = (tile & 3) * 64;
    int row0 = bc * CH;
    __shared__ float Ct[64][65], Bt_[64][65];
    int tq = (threadIdx.x >> 4) * 4;
    int sq = (threadIdx.x & 15) * 4;
    float acc[4][4] = {};
    for (int nh = 0; nh < 2; nh++) {
        __syncthreads();
        int r = threadIdx.x >> 2, cc = (threadIdx.x & 3) * 16;
        for (int q = 0; q < 16; q += 4) {
            ushort4 cv = *(const ushort4*)&xbc[(size_t)(row0 + tb0 + r) * CDIM + (DI + DS) + nh * 64 + cc + q];
            ushort4 bv = *(const ushort4*)&xbc[(size_t)(row0 + sb0 + r) * CDIM + DI + nh * 64 + cc + q];
            Ct[r][cc + q] = bf2f(cv.x); Ct[r][cc + q + 1] = bf2f(cv.y); Ct[r][cc + q + 2] = bf2f(cv.z); Ct[r][cc + q + 3] = bf2f(cv.w);
            Bt_[r][cc + q] = bf2f(bv.x); Bt_[r][cc + q + 1] = bf2f(bv.y); Bt_[r][cc + q + 2] = bf2f(bv.z); Bt_[r][cc + q + 3] = bf2f(bv.w);
        }
        __syncthreads();
        for (int n = 0; n < 64; n++) {
            float a[4], bb[4];
            for (int i = 0; i < 4; i++) a[i] = Ct[tq + i][n];
            for (int j = 0; j < 4; j++) bb[j] = Bt_[sq + j][n];
            for (int i = 0; i < 4; i++)
                for (int j = 0; j < 4; j++) acc[i][j] += a[i] * bb[j];
        }
    }
    for (int i = 0; i < 4; i++)
        for (int j = 0; j < 4; j++)
            G[((size_t)(row0 + tb0 + tq + i)) * CH + sb0 + sq + j] = acc[i][j];
}

// ---- 5: states[p,n] = sum_t Bm[t,n]*exp(Acs[255]-Acs[t])*xdt[t,p] per (b,c,h) ----
__global__ __launch_bounds__(256) void states_kernel(const u16* __restrict__ xbc, const float* __restrict__ dtb,
                                                     const float* __restrict__ acs_g, float* __restrict__ states) {
    int bid = blockIdx.x;                 // (b,c,h)
    int h = bid & 63, c = (bid >> 6) & 7, b = bid >> 9;
    int row0 = b * L_SZ + c * CH;
    const float* acs = acs_g + ((size_t)((b * NH + h) * NCK + c)) * CH;
    __shared__ float decay[256];
    __shared__ float Xs[32][64];
    __shared__ float Bs[32][128];
    int tid = threadIdx.x;
    decay[tid] = expf(acs[255] - acs[tid]);
    float acc[8][4] = {};
    int pb = (tid >> 5) * 8, nl = tid & 31;
    for (int t0 = 0; t0 < CH; t0 += 32) {
        __syncthreads();
        {
            int r = tid >> 3, cc = (tid & 7) * 8;
            int row = row0 + t0 + r;
            float dscale = dtb[row * NH + h] * decay[t0 + r];
            for (int q = 0; q < 8; q += 4) {
                ushort4 xv = *(const ushort4*)&xbc[(size_t)row * CDIM + h * HD + cc + q];
                Xs[r][cc + q] = bf2f(xv.x) * dscale; Xs[r][cc + q + 1] = bf2f(xv.y) * dscale;
                Xs[r][cc + q + 2] = bf2f(xv.z) * dscale; Xs[r][cc + q + 3] = bf2f(xv.w) * dscale;
            }
            int c2 = (tid & 7) * 16;
            for (int q = 0; q < 16; q += 4) {
                ushort4 bv = *(const ushort4*)&xbc[(size_t)row * CDIM + DI + c2 + q];
                Bs[r][c2 + q] = bf2f(bv.x); Bs[r][c2 + q + 1] = bf2f(bv.y);
                Bs[r][c2 + q + 2] = bf2f(bv.z); Bs[r][c2 + q + 3] = bf2f(bv.w);
            }
        }
        __syncthreads();
        for (int t = 0; t < 32; t++) {
            float xv[8], bv[4];
            for (int i = 0; i < 8; i++) xv[i] = Xs[t][pb + i];
            for (int j = 0; j < 4; j++) bv[j] = Bs[t][nl + 32 * j];
            for (int i = 0; i < 8; i++)
                for (int j = 0; j < 4; j++) acc[i][j] += xv[i] * bv[j];
        }
    }
    float* st = states + (size_t)bid * (HD * DS);
    for (int i = 0; i < 8; i++)
        for (int j = 0; j < 4; j++) st[(pb + i) * DS + nl + 32 * j] = acc[i][j];
}

// ---- 6: inter-chunk scan IN PLACE: states[c] <- carry_c; carry = carry*exp(S_c)+states_c ----
__global__ void cscan_kernel(float* __restrict__ states, const float* __restrict__ acs_g) {
    int bid = blockIdx.x;                 // 128 = b*64 + h
    int h = bid & 63, b = bid >> 6;
    int tid = threadIdx.x;
    float4 carry[8];
    for (int i = 0; i < 8; i++) carry[i] = make_float4(0.f, 0.f, 0.f, 0.f);
    for (int c = 0; c < NCK; c++) {
        size_t base = ((size_t)((b * NCK + c) * NH + h)) * (HD * DS);
        float g = expf(acs_g[((size_t)((b * NH + h) * NCK + c)) * CH + (CH - 1)]);
        float4* sp = (float4*)(states + base);
        for (int i = 0; i < 8; i++) {
            int idx = tid + 256 * i;
            float4 s = sp[idx];
            sp[idx] = carry[i];
            carry[i].x = carry[i].x * g + s.x;
            carry[i].y = carry[i].y * g + s.y;
            carry[i].z = carry[i].z * g + s.z;
            carry[i].w = carry[i].w * g + s.w;
        }
    }
}

// ---- 7: y = Yo + Yd + D_skip*x per (b,c,h) ----
__global__ __launch_bounds__(256) void y_kernel(const u16* __restrict__ xbc, const float* __restrict__ dtb,
                                                const float* __restrict__ acs_g, const float* __restrict__ G,
                                                const float* __restrict__ init_st, const float* __restrict__ D_skip,
                                                u16* __restrict__ y) {
    int bid = blockIdx.x;                 // (b,c,h)
    int h = bid & 63, c = (bid >> 6) & 7, b = bid >> 9;
    int bc = b * NCK + c;
    int row0 = b * L_SZ + c * CH;
    int t = threadIdx.x;
    __shared__ float acs[256];
    __shared__ float Ss[HD * DS];         // init_st[p][n]
    __shared__ float Xs[64][64];
    acs[t] = acs_g[((size_t)((b * NH + h) * NCK + c)) * CH + t];
    {
        const float4* sg = (const float4*)(init_st + ((size_t)(bc * NH + h)) * (HD * DS));
        float4* ds = (float4*)Ss;
        for (int i = 0; i < 8; i++) ds[t + 256 * i] = sg[t + 256 * i];
    }
    __syncthreads();
    float acc[64];
    for (int p = 0; p < 64; p++) acc[p] = 0.f;
    // Yo: sum_n Cm[t,n] * Ss[p,n], scaled by exp(Acs[t])
    const ushort4* crow = (const ushort4*)(xbc + (size_t)(row0 + t) * CDIM + DI + DS);
    for (int n4 = 0; n4 < 32; n4++) {
        ushort4 cu = crow[n4];
        float cx = bf2f(cu.x), cy = bf2f(cu.y), cz = bf2f(cu.z), cw = bf2f(cu.w);
        int n = n4 * 4;
        for (int p = 0; p < 64; p++) {
            const float4 sv = *(const float4*)&Ss[p * DS + n];
            acc[p] += cx * sv.x + cy * sv.y + cz * sv.z + cw * sv.w;
        }
    }
    float eA = expf(acs[t]);
    for (int p = 0; p < 64; p++) acc[p] *= eA;
    // Yd: sum_{s<=t} G[t,s]*exp(Acs[t]-Acs[s]) * xdt[s,p]
    const float* grow = G + ((size_t)(bc * CH + t)) * CH;
    for (int s0 = 0; s0 < CH; s0 += 64) {
        __syncthreads();
        {
            int r = t >> 2, cc = (t & 3) * 16;
            int row = row0 + s0 + r;
            float dv = dtb[row * NH + h];
            for (int q = 0; q < 16; q += 4) {
                ushort4 xv = *(const ushort4*)&xbc[(size_t)row * CDIM + h * HD + cc + q];
                Xs[r][cc + q] = bf2f(xv.x) * dv; Xs[r][cc + q + 1] = bf2f(xv.y) * dv;
                Xs[r][cc + q + 2] = bf2f(xv.z) * dv; Xs[r][cc + q + 3] = bf2f(xv.w) * dv;
            }
        }
        __syncthreads();
        if (t >= s0) {
            int send = t - s0 + 1; if (send > 64) send = 64;
            for (int sl = 0; sl < send; sl++) {
                int s = s0 + sl;
                float w = grow[s] * expf(acs[t] - acs[s]);
                for (int p = 0; p < 64; p += 4) {
                    float4 xv = *(const float4*)&Xs[sl][p];
                    acc[p] += w * xv.x; acc[p + 1] += w * xv.y;
                    acc[p + 2] += w * xv.z; acc[p + 3] += w * xv.w;
                }
            }
        }
    }
    float dsk = D_skip[h];
    const u16* xrow = xbc + (size_t)(row0 + t) * CDIM + h * HD;
    u16* yrow = y + (size_t)(row0 + t) * DI + h * HD;
    for (int p = 0; p < 64; p += 4) {
        ushort4 xv = *(const ushort4*)&xrow[p];
        ushort4 o;
        o.x = f2bf(acc[p] + dsk * bf2f(xv.x));
        o.y = f2bf(acc[p + 1] + dsk * bf2f(xv.y));
        o.z = f2bf(acc[p + 2] + dsk * bf2f(xv.z));
        o.w = f2bf(acc[p + 3] + dsk * bf2f(xv.w));
        *(ushort4*)&yrow[p] = o;
    }
}

// ---- 8: out = (y * silu(z)) * rsqrt(mean(yg^2)+eps) * norm_w ----
__global__ void final_kernel(const u16* __restrict__ y, const u16* __restrict__ zx,
                             const float* __restrict__ norm_w, float* __restrict__ out) {
    int row = blockIdx.x;
    int tid = threadIdx.x;
    __shared__ float red[4];
    float yg[16];
    float ss = 0.f;
    for (int i = 0; i < 16; i++) {
        int col = tid + 256 * i;
        float z = bf2f(zx[(size_t)row * NP + col]);
        float g = bf2f(y[(size_t)row * DI + col]) * (z / (1.f + expf(-z)));
        yg[i] = g; ss += g * g;
    }
    for (int off = 32; off; off >>= 1) ss += __shfl_down(ss, off);
    if ((tid & 63) == 0) red[tid >> 6] = ss;
    __syncthreads();
    if (tid == 0) red[0] = red[0] + red[1] + red[2] + red[3];
    __syncthreads();
    float inv = rsqrtf(red[0] / (float)DI + 1e-5f);
    for (int i = 0; i < 16; i++) {
        int col = tid + 256 * i;
        out[(size_t)row * DI + col] = yg[i] * inv * norm_w[col];
    }
}

extern "C" void kernel_launch(void* const* d_in, const int* in_sizes, int n_in,
                              void* d_out, int out_size, void* d_ws, size_t ws_size,
                              hipStream_t stream) {
    const float* u       = (const float*)d_in[0];
    const float* w_in    = (const float*)d_in[1];
    const float* conv_w  = (const float*)d_in[2];
    const float* conv_b  = (const float*)d_in[3];
    const float* dt_bias = (const float*)d_in[4];
    const float* A_log   = (const float*)d_in[5];
    const float* D_skip  = (const float*)d_in[6];
    const float* norm_w  = (const float*)d_in[7];
    float* out = (float*)d_out;

    // ---- workspace layout (bytes), total = 179,306,496 (~171 MiB) ----
    // zx   bf16 [MROWS][NP]   @ 0          70,254,592
    // R = 70,254,592 (aliased region):
    //   phase1: ubf bf16 @R (16,777,216); wtb bf16 @R+16,777,216 (35,127,296)
    //   phase2: xbc bf16 @R (35,651,584); dtb f32 @R+35,651,584 (1,048,576);
    //           acs f32 @R+36,700,160 (1,048,576); G f32 @R+37,748,736 (4,194,304);
    //           stat f32 @R+41,943,040 (33,554,432); yb bf16 @R+75,497,472 (33,554,432)
    const size_t NEEDED = 179306496ull;
    if (ws_size < NEEDED) return;   // diagnostic: clean absmax-fail instead of OOB crash

    char* ws = (char*)d_ws;
    const size_t R = 70254592ull;
    u16*   zx   = (u16*)ws;
    u16*   ubf  = (u16*)(ws + R);
    u16*   wtb  = (u16*)(ws + R + 16777216);
    u16*   xbc  = (u16*)(ws + R);
    float* dtb  = (float*)(ws + R + 35651584);
    float* acs  = (float*)(ws + R + 36700160);
    float* G    = (float*)(ws + R + 37748736);
    float* stat = (float*)(ws + R + 41943040);
    u16*   yb   = (u16*)(ws + R + 75497472);

    cvt_u_kernel<<<8192, 256, 0, stream>>>(u, ubf);
    transpose_w_kernel<<<dim3(268, 64), 256, 0, stream>>>(w_in, wtb);
    gemm_kernel<<<dim3(67, 32), 256, 0, stream>>>(ubf, wtb, zx);
    conv_silu_kernel<<<dim3(17, 4096), 256, 0, stream>>>(zx, conv_w, conv_b, xbc);
    dt_scan_kernel<<<1024, 256, 0, stream>>>(zx, dt_bias, A_log, dtb, acs);
    g_kernel<<<256, 256, 0, stream>>>(xbc, G);
    states_kernel<<<1024, 256, 0, stream>>>(xbc, dtb, acs, stat);
    cscan_kernel<<<128, 256, 0, stream>>>(stat, acs);
    y_kernel<<<1024, 256, 0, stream>>>(xbc, dtb, acs, G, stat, D_skip, yb);
    final_kernel<<<4096, 256, 0, stream>>>(yb, zx, norm_w, out);
}

// Round 4
// 980.744 us; speedup vs baseline: 1.4483x; 1.4483x over previous
//
#include <hip/hip_runtime.h>
#include <hip/hip_bf16.h>

// ---- problem constants ----
#define B_SZ   2
#define L_SZ   2048
#define DM     2048
#define DS     128
#define DCV    4
#define HD     64
#define CH     256
#define DI     4096
#define NH     64
#define DIP    8512
#define CDIM   4352
#define NP     8576      // DIP padded to 67*128
#define MROWS  4096      // B_SZ*L_SZ
#define NCK    8         // L_SZ/CH

typedef __attribute__((ext_vector_type(8))) short bf16x8;
typedef __attribute__((ext_vector_type(4))) float f32x4;
typedef unsigned short u16;

__device__ __forceinline__ u16 f2bf(float f) {
    union { float f; unsigned u; } c; c.f = f;
    unsigned r = c.u + 0x7fffu + ((c.u >> 16) & 1u);
    return (u16)(r >> 16);
}
__device__ __forceinline__ float bf2f(u16 b) {
    union { unsigned u; float f; } c; c.u = ((unsigned)b) << 16; return c.f;
}

// async global->LDS copy, 16 B per lane (global_load_lds_dwordx4)
__device__ __forceinline__ void async16(const u16* g, u16* l) {
    __builtin_amdgcn_global_load_lds(
        (const __attribute__((address_space(1))) unsigned int*)(g),
        (__attribute__((address_space(3))) unsigned int*)(l),
        16, 0, 0);
}

// ---- 0a: u f32 -> bf16 ----
__global__ void cvt_u_kernel(const float* __restrict__ u, u16* __restrict__ ub) {
    int i = blockIdx.x * 256 + threadIdx.x;
    float4 v = ((const float4*)u)[i];
    ushort4 o;
    o.x = f2bf(v.x); o.y = f2bf(v.y); o.z = f2bf(v.z); o.w = f2bf(v.w);
    ((ushort4*)ub)[i] = o;
}

// ---- 0b: w_in (K=2048 x DIP) f32 -> w_inT (NP x K) bf16, zero-pad rows >= DIP ----
__global__ void transpose_w_kernel(const float* __restrict__ w, u16* __restrict__ wt) {
    __shared__ float tile[32][33];
    int n0 = blockIdx.x * 32, k0 = blockIdx.y * 32;
    int tx = threadIdx.x & 31, ty = threadIdx.x >> 5;
    for (int j = 0; j < 32; j += 8) {
        int k = k0 + ty + j, n = n0 + tx;
        tile[ty + j][tx] = (n < DIP) ? w[(size_t)k * DIP + n] : 0.f;
    }
    __syncthreads();
    for (int j = 0; j < 32; j += 8) {
        int n = n0 + ty + j, k = k0 + tx;
        wt[(size_t)n * DM + k] = f2bf(tile[tx][ty + j]);
    }
}

// ---- 1: GEMM zxbcdt = u @ w_in -> bf16 [MROWS][NP]; m97 structure + grouped-M swizzle ----
#define GEMM_NM 32        // m tiles
#define GEMM_NN 67        // n tiles
#define GEMM_GM 8         // group size along m (32 % 8 == 0)
__global__ __launch_bounds__(256) void gemm_kernel(const u16* __restrict__ A,
                                                   const u16* __restrict__ Bt,
                                                   u16* __restrict__ C) {
    __shared__ u16 As[128 * 64];   // NO padding: global_load_lds needs contiguous lane order
    __shared__ u16 Bs[128 * 64];
    // grouped-M swizzle: consecutive ids cycle m within a group of 8, sharing the B tile;
    // ids == x (mod 8) land on one XCD and sweep a single m-row (A slice pinned in L2).
    const int bid = blockIdx.x;
    const int width = GEMM_GM * GEMM_NN;          // 536
    const int group = bid / width;
    const int rem = bid - group * width;
    const int pid_m = group * GEMM_GM + (rem % GEMM_GM);
    const int pid_n = rem / GEMM_GM;
    const int m0 = pid_m * 128, n0 = pid_n * 128;

    const int tid = threadIdx.x;
    const int lane = tid & 63, w = tid >> 6;
    const int wm = (w >> 1) * 64, wn = (w & 1) * 64;
    const int quad = lane >> 4, lm = lane & 15;
    const int lr = lane >> 3;          // 0..7  (row within 8-row stripe)
    const int lc = (lane & 7) * 8;     // 0..56 (element col)
    f32x4 acc[4][4] = {};
    for (int k0 = 0; k0 < DM; k0 += 64) {
        __syncthreads();               // all waves done reading LDS from prev iter
        for (int j = 0; j < 4; j++) {
            int row = w * 32 + j * 8 + lr;
            async16(A  + (size_t)(m0 + row) * DM + k0 + lc, As + row * 64 + lc);
            async16(Bt + (size_t)(n0 + row) * DM + k0 + lc, Bs + row * 64 + lc);
        }
        __syncthreads();               // compiler drains vmcnt(0) before barrier
        for (int ks = 0; ks < 64; ks += 32) {
            bf16x8 af[4], bfr[4];
            for (int i = 0; i < 4; i++) af[i]  = *(const bf16x8*)(As + (wm + i * 16 + lm) * 64 + ks + quad * 8);
            for (int j = 0; j < 4; j++) bfr[j] = *(const bf16x8*)(Bs + (wn + j * 16 + lm) * 64 + ks + quad * 8);
            for (int i = 0; i < 4; i++)
                for (int j = 0; j < 4; j++)
                    acc[i][j] = __builtin_amdgcn_mfma_f32_16x16x32_bf16(af[i], bfr[j], acc[i][j], 0, 0, 0);
        }
    }
    for (int i = 0; i < 4; i++)
        for (int j = 0; j < 4; j++)
            for (int r = 0; r < 4; r++) {
                int gm = m0 + wm + i * 16 + quad * 4 + r;
                int gn = n0 + wn + j * 16 + lm;
                C[(size_t)gm * NP + gn] = f2bf(acc[i][j][r]);
            }
}

// ---- 2: causal depthwise conv(4) + SiLU ----
__global__ void conv_silu_kernel(const u16* __restrict__ zx, const float* __restrict__ cw,
                                 const float* __restrict__ cb, u16* __restrict__ xbc) {
    int c = blockIdx.x * 256 + threadIdx.x;   // < CDIM
    int row = blockIdx.y;                     // 0..4095
    int l = row & (L_SZ - 1);
    float acc = cb[c];
    for (int k = 0; k < DCV; k++) {
        int ls = l - 3 + k;
        if (ls >= 0) acc += bf2f(zx[(size_t)(row - 3 + k) * NP + DI + c]) * cw[c * DCV + k];
    }
    float s = acc / (1.f + expf(-acc));
    xbc[(size_t)row * CDIM + c] = f2bf(s);
}

// ---- 3: dt = softplus(raw+bias), per-chunk cumsum of dA ----
__global__ void dt_scan_kernel(const u16* __restrict__ zx, const float* __restrict__ dt_bias,
                               const float* __restrict__ A_log, float* __restrict__ dtb,
                               float* __restrict__ acs) {
    int bid = blockIdx.x;                 // 1024 = b*512 + c*64 + h
    int h = bid & 63, c = (bid >> 6) & 7, b = bid >> 9;
    int t = threadIdx.x;
    int row = b * L_SZ + c * CH + t;
    float raw = bf2f(zx[(size_t)row * NP + (DI + CDIM) + h]) + dt_bias[h];
    float dtv = (raw > 20.f) ? raw : log1pf(expf(raw));
    float dA = dtv * (-expf(A_log[h]));
    dtb[row * NH + h] = dtv;
    __shared__ float sc[256];
    sc[t] = dA;
    for (int off = 1; off < 256; off <<= 1) {
        __syncthreads();
        float v = (t >= off) ? sc[t - off] : 0.f;
        __syncthreads();
        sc[t] += v;
    }
    acs[((size_t)((b * NH + h) * NCK + c)) * CH + t] = sc[t];
}

// ---- 4: G[t,s] = sum_n Cm[t,n]*Bm[s,n] per (b,c) ----
__global__ void g_kernel(const u16* __restrict__ xbc, float* __restrict__ G) {
    int blk = blockIdx.x;         // 256 = bc*16 + tile
    int bc = blk >> 4;
    int tile = blk & 15;
    int tb0 = (tile >> 2) * 64, sb0 = (tile & 3) * 64;
    int row0 = bc * CH;
    __shared__ float Ct[64][65], Bt_[64][65];
    int tq = (threadIdx.x >> 4) * 4;
    int sq = (threadIdx.x & 15) * 4;
    float acc[4][4] = {};
    for (int nh = 0; nh < 2; nh++) {
        __syncthreads();
        int r = threadIdx.x >> 2, cc = (threadIdx.x & 3) * 16;
        for (int q = 0; q < 16; q += 4) {
            ushort4 cv = *(const ushort4*)&xbc[(size_t)(row0 + tb0 + r) * CDIM + (DI + DS) + nh * 64 + cc + q];
            ushort4 bv = *(const ushort4*)&xbc[(size_t)(row0 + sb0 + r) * CDIM + DI + nh * 64 + cc + q];
            Ct[r][cc + q] = bf2f(cv.x); Ct[r][cc + q + 1] = bf2f(cv.y); Ct[r][cc + q + 2] = bf2f(cv.z); Ct[r][cc + q + 3] = bf2f(cv.w);
            Bt_[r][cc + q] = bf2f(bv.x); Bt_[r][cc + q + 1] = bf2f(bv.y); Bt_[r][cc + q + 2] = bf2f(bv.z); Bt_[r][cc + q + 3] = bf2f(bv.w);
        }
        __syncthreads();
        for (int n = 0; n < 64; n++) {
            float a[4], bb[4];
            for (int i = 0; i < 4; i++) a[i] = Ct[tq + i][n];
            for (int j = 0; j < 4; j++) bb[j] = Bt_[sq + j][n];
            for (int i = 0; i < 4; i++)
                for (int j = 0; j < 4; j++) acc[i][j] += a[i] * bb[j];
        }
    }
    for (int i = 0; i < 4; i++)
        for (int j = 0; j < 4; j++)
            G[((size_t)(row0 + tb0 + tq + i)) * CH + sb0 + sq + j] = acc[i][j];
}

// ---- 5: states[p,n] = sum_t Bm[t,n]*exp(Acs[255]-Acs[t])*xdt[t,p] per (b,c,h) ----
__global__ __launch_bounds__(256) void states_kernel(const u16* __restrict__ xbc, const float* __restrict__ dtb,
                                                     const float* __restrict__ acs_g, float* __restrict__ states) {
    int bid = blockIdx.x;                 // (b,c,h)
    int h = bid & 63, c = (bid >> 6) & 7, b = bid >> 9;
    int row0 = b * L_SZ + c * CH;
    const float* acs = acs_g + ((size_t)((b * NH + h) * NCK + c)) * CH;
    __shared__ float decay[256];
    __shared__ float Xs[32][64];
    __shared__ float Bs[32][128];
    int tid = threadIdx.x;
    decay[tid] = expf(acs[255] - acs[tid]);
    float acc[8][4] = {};
    int pb = (tid >> 5) * 8, nl = tid & 31;
    for (int t0 = 0; t0 < CH; t0 += 32) {
        __syncthreads();
        {
            int r = tid >> 3, cc = (tid & 7) * 8;
            int row = row0 + t0 + r;
            float dscale = dtb[row * NH + h] * decay[t0 + r];
            for (int q = 0; q < 8; q += 4) {
                ushort4 xv = *(const ushort4*)&xbc[(size_t)row * CDIM + h * HD + cc + q];
                Xs[r][cc + q] = bf2f(xv.x) * dscale; Xs[r][cc + q + 1] = bf2f(xv.y) * dscale;
                Xs[r][cc + q + 2] = bf2f(xv.z) * dscale; Xs[r][cc + q + 3] = bf2f(xv.w) * dscale;
            }
            int c2 = (tid & 7) * 16;
            for (int q = 0; q < 16; q += 4) {
                ushort4 bv = *(const ushort4*)&xbc[(size_t)row * CDIM + DI + c2 + q];
                Bs[r][c2 + q] = bf2f(bv.x); Bs[r][c2 + q + 1] = bf2f(bv.y);
                Bs[r][c2 + q + 2] = bf2f(bv.z); Bs[r][c2 + q + 3] = bf2f(bv.w);
            }
        }
        __syncthreads();
        for (int t = 0; t < 32; t++) {
            float xv[8], bv[4];
            for (int i = 0; i < 8; i++) xv[i] = Xs[t][pb + i];
            for (int j = 0; j < 4; j++) bv[j] = Bs[t][nl + 32 * j];
            for (int i = 0; i < 8; i++)
                for (int j = 0; j < 4; j++) acc[i][j] += xv[i] * bv[j];
        }
    }
    float* st = states + (size_t)bid * (HD * DS);
    for (int i = 0; i < 8; i++)
        for (int j = 0; j < 4; j++) st[(pb + i) * DS + nl + 32 * j] = acc[i][j];
}

// ---- 6: inter-chunk scan IN PLACE ----
__global__ void cscan_kernel(float* __restrict__ states, const float* __restrict__ acs_g) {
    int bid = blockIdx.x;                 // 128 = b*64 + h
    int h = bid & 63, b = bid >> 6;
    int tid = threadIdx.x;
    float4 carry[8];
    for (int i = 0; i < 8; i++) carry[i] = make_float4(0.f, 0.f, 0.f, 0.f);
    for (int c = 0; c < NCK; c++) {
        size_t base = ((size_t)((b * NCK + c) * NH + h)) * (HD * DS);
        float g = expf(acs_g[((size_t)((b * NH + h) * NCK + c)) * CH + (CH - 1)]);
        float4* sp = (float4*)(states + base);
        for (int i = 0; i < 8; i++) {
            int idx = tid + 256 * i;
            float4 s = sp[idx];
            sp[idx] = carry[i];
            carry[i].x = carry[i].x * g + s.x;
            carry[i].y = carry[i].y * g + s.y;
            carry[i].z = carry[i].z * g + s.z;
            carry[i].w = carry[i].w * g + s.w;
        }
    }
}

// ---- 7: y = Yo + Yd + D_skip*x per (b,c,h) ----
__global__ __launch_bounds__(256) void y_kernel(const u16* __restrict__ xbc, const float* __restrict__ dtb,
                                                const float* __restrict__ acs_g, const float* __restrict__ G,
                                                const float* __restrict__ init_st, const float* __restrict__ D_skip,
                                                u16* __restrict__ y) {
    int bid = blockIdx.x;                 // (b,c,h)
    int h = bid & 63, c = (bid >> 6) & 7, b = bid >> 9;
    int bc = b * NCK + c;
    int row0 = b * L_SZ + c * CH;
    int t = threadIdx.x;
    __shared__ float acs[256];
    __shared__ float Ss[HD * DS];
    __shared__ float Xs[64][64];
    acs[t] = acs_g[((size_t)((b * NH + h) * NCK + c)) * CH + t];
    {
        const float4* sg = (const float4*)(init_st + ((size_t)(bc * NH + h)) * (HD * DS));
        float4* ds = (float4*)Ss;
        for (int i = 0; i < 8; i++) ds[t + 256 * i] = sg[t + 256 * i];
    }
    __syncthreads();
    float acc[64];
    for (int p = 0; p < 64; p++) acc[p] = 0.f;
    const ushort4* crow = (const ushort4*)(xbc + (size_t)(row0 + t) * CDIM + DI + DS);
    for (int n4 = 0; n4 < 32; n4++) {
        ushort4 cu = crow[n4];
        float cx = bf2f(cu.x), cy = bf2f(cu.y), cz = bf2f(cu.z), cw = bf2f(cu.w);
        int n = n4 * 4;
        for (int p = 0; p < 64; p++) {
            const float4 sv = *(const float4*)&Ss[p * DS + n];
            acc[p] += cx * sv.x + cy * sv.y + cz * sv.z + cw * sv.w;
        }
    }
    float eA = expf(acs[t]);
    for (int p = 0; p < 64; p++) acc[p] *= eA;
    const float* grow = G + ((size_t)(bc * CH + t)) * CH;
    for (int s0 = 0; s0 < CH; s0 += 64) {
        __syncthreads();
        {
            int r = t >> 2, cc = (t & 3) * 16;
            int row = row0 + s0 + r;
            float dv = dtb[row * NH + h];
            for (int q = 0; q < 16; q += 4) {
                ushort4 xv = *(const ushort4*)&xbc[(size_t)row * CDIM + h * HD + cc + q];
                Xs[r][cc + q] = bf2f(xv.x) * dv; Xs[r][cc + q + 1] = bf2f(xv.y) * dv;
                Xs[r][cc + q + 2] = bf2f(xv.z) * dv; Xs[r][cc + q + 3] = bf2f(xv.w) * dv;
            }
        }
        __syncthreads();
        if (t >= s0) {
            int send = t - s0 + 1; if (send > 64) send = 64;
            for (int sl = 0; sl < send; sl++) {
                int s = s0 + sl;
                float w = grow[s] * expf(acs[t] - acs[s]);
                for (int p = 0; p < 64; p += 4) {
                    float4 xv = *(const float4*)&Xs[sl][p];
                    acc[p] += w * xv.x; acc[p + 1] += w * xv.y;
                    acc[p + 2] += w * xv.z; acc[p + 3] += w * xv.w;
                }
            }
        }
    }
    float dsk = D_skip[h];
    const u16* xrow = xbc + (size_t)(row0 + t) * CDIM + h * HD;
    u16* yrow = y + (size_t)(row0 + t) * DI + h * HD;
    for (int p = 0; p < 64; p += 4) {
        ushort4 xv = *(const ushort4*)&xrow[p];
        ushort4 o;
        o.x = f2bf(acc[p] + dsk * bf2f(xv.x));
        o.y = f2bf(acc[p + 1] + dsk * bf2f(xv.y));
        o.z = f2bf(acc[p + 2] + dsk * bf2f(xv.z));
        o.w = f2bf(acc[p + 3] + dsk * bf2f(xv.w));
        *(ushort4*)&yrow[p] = o;
    }
}

// ---- 8: out = (y * silu(z)) * rsqrt(mean(yg^2)+eps) * norm_w ----
__global__ void final_kernel(const u16* __restrict__ y, const u16* __restrict__ zx,
                             const float* __restrict__ norm_w, float* __restrict__ out) {
    int row = blockIdx.x;
    int tid = threadIdx.x;
    __shared__ float red[4];
    float yg[16];
    float ss = 0.f;
    for (int i = 0; i < 16; i++) {
        int col = tid + 256 * i;
        float z = bf2f(zx[(size_t)row * NP + col]);
        float g = bf2f(y[(size_t)row * DI + col]) * (z / (1.f + expf(-z)));
        yg[i] = g; ss += g * g;
    }
    for (int off = 32; off; off >>= 1) ss += __shfl_down(ss, off);
    if ((tid & 63) == 0) red[tid >> 6] = ss;
    __syncthreads();
    if (tid == 0) red[0] = red[0] + red[1] + red[2] + red[3];
    __syncthreads();
    float inv = rsqrtf(red[0] / (float)DI + 1e-5f);
    for (int i = 0; i < 16; i++) {
        int col = tid + 256 * i;
        out[(size_t)row * DI + col] = yg[i] * inv * norm_w[col];
    }
}

extern "C" void kernel_launch(void* const* d_in, const int* in_sizes, int n_in,
                              void* d_out, int out_size, void* d_ws, size_t ws_size,
                              hipStream_t stream) {
    const float* u       = (const float*)d_in[0];
    const float* w_in    = (const float*)d_in[1];
    const float* conv_w  = (const float*)d_in[2];
    const float* conv_b  = (const float*)d_in[3];
    const float* dt_bias = (const float*)d_in[4];
    const float* A_log   = (const float*)d_in[5];
    const float* D_skip  = (const float*)d_in[6];
    const float* norm_w  = (const float*)d_in[7];
    float* out = (float*)d_out;

    const size_t NEEDED = 179306496ull;
    if (ws_size < NEEDED) return;

    char* ws = (char*)d_ws;
    const size_t R = 70254592ull;
    u16*   zx   = (u16*)ws;
    u16*   ubf  = (u16*)(ws + R);
    u16*   wtb  = (u16*)(ws + R + 16777216);
    u16*   xbc  = (u16*)(ws + R);
    float* dtb  = (float*)(ws + R + 35651584);
    float* acs  = (float*)(ws + R + 36700160);
    float* G    = (float*)(ws + R + 37748736);
    float* stat = (float*)(ws + R + 41943040);
    u16*   yb   = (u16*)(ws + R + 75497472);

    cvt_u_kernel<<<8192, 256, 0, stream>>>(u, ubf);
    transpose_w_kernel<<<dim3(268, 64), 256, 0, stream>>>(w_in, wtb);
    gemm_kernel<<<GEMM_NM * GEMM_NN, 256, 0, stream>>>(ubf, wtb, zx);
    conv_silu_kernel<<<dim3(17, 4096), 256, 0, stream>>>(zx, conv_w, conv_b, xbc);
    dt_scan_kernel<<<1024, 256, 0, stream>>>(zx, dt_bias, A_log, dtb, acs);
    g_kernel<<<256, 256, 0, stream>>>(xbc, G);
    states_kernel<<<1024, 256, 0, stream>>>(xbc, dtb, acs, stat);
    cscan_kernel<<<128, 256, 0, stream>>>(stat, acs);
    y_kernel<<<1024, 256, 0, stream>>>(xbc, dtb, acs, G, stat, D_skip, yb);
    final_kernel<<<4096, 256, 0, stream>>>(yb, zx, norm_w, out);
}

// Round 5
// 731.136 us; speedup vs baseline: 1.9427x; 1.3414x over previous
//
#include <hip/hip_runtime.h>
#include <hip/hip_bf16.h>

// ---- problem constants ----
#define B_SZ   2
#define L_SZ   2048
#define DM     2048
#define DS     128
#define DCV    4
#define HD     64
#define CH     256
#define DI     4096
#define NH     64
#define DIP    8512
#define CDIM   4352
#define NP     8576      // DIP padded to 67*128
#define MROWS  4096      // B_SZ*L_SZ
#define NCK    8         // L_SZ/CH

typedef __attribute__((ext_vector_type(8))) short bf16x8;
typedef __attribute__((ext_vector_type(4))) float f32x4;
typedef unsigned short u16;

__device__ __forceinline__ u16 f2bf(float f) {
    union { float f; unsigned u; } c; c.f = f;
    unsigned r = c.u + 0x7fffu + ((c.u >> 16) & 1u);
    return (u16)(r >> 16);
}
__device__ __forceinline__ float bf2f(u16 b) {
    union { unsigned u; float f; } c; c.u = ((unsigned)b) << 16; return c.f;
}

// async global->LDS copy, 16 B per lane (global_load_lds_dwordx4)
__device__ __forceinline__ void async16(const u16* g, u16* l) {
    __builtin_amdgcn_global_load_lds(
        (const __attribute__((address_space(1))) unsigned int*)(g),
        (__attribute__((address_space(3))) unsigned int*)(l),
        16, 0, 0);
}

// ---- 0a: u f32 -> bf16 ----
__global__ void cvt_u_kernel(const float* __restrict__ u, u16* __restrict__ ub) {
    int i = blockIdx.x * 256 + threadIdx.x;
    float4 v = ((const float4*)u)[i];
    ushort4 o;
    o.x = f2bf(v.x); o.y = f2bf(v.y); o.z = f2bf(v.z); o.w = f2bf(v.w);
    ((ushort4*)ub)[i] = o;
}

// ---- 0b: w_in (K=2048 x DIP) f32 -> w_inT (NP x K) bf16, zero-pad rows >= DIP ----
__global__ void transpose_w_kernel(const float* __restrict__ w, u16* __restrict__ wt) {
    __shared__ float tile[32][33];
    int n0 = blockIdx.x * 32, k0 = blockIdx.y * 32;
    int tx = threadIdx.x & 31, ty = threadIdx.x >> 5;
    for (int j = 0; j < 32; j += 8) {
        int k = k0 + ty + j, n = n0 + tx;
        tile[ty + j][tx] = (n < DIP) ? w[(size_t)k * DIP + n] : 0.f;
    }
    __syncthreads();
    for (int j = 0; j < 32; j += 8) {
        int n = n0 + ty + j, k = k0 + tx;
        wt[(size_t)n * DM + k] = f2bf(tile[tx][ty + j]);
    }
}

// ---- 1: GEMM zxbcdt = u @ w_in -> bf16 [MROWS][NP]; m97 structure + grouped-M swizzle ----
#define GEMM_NM 32
#define GEMM_NN 67
#define GEMM_GM 8
__global__ __launch_bounds__(256) void gemm_kernel(const u16* __restrict__ A,
                                                   const u16* __restrict__ Bt,
                                                   u16* __restrict__ C) {
    __shared__ u16 As[128 * 64];
    __shared__ u16 Bs[128 * 64];
    const int bid = blockIdx.x;
    const int width = GEMM_GM * GEMM_NN;
    const int group = bid / width;
    const int rem = bid - group * width;
    const int pid_m = group * GEMM_GM + (rem % GEMM_GM);
    const int pid_n = rem / GEMM_GM;
    const int m0 = pid_m * 128, n0 = pid_n * 128;

    const int tid = threadIdx.x;
    const int lane = tid & 63, w = tid >> 6;
    const int wm = (w >> 1) * 64, wn = (w & 1) * 64;
    const int quad = lane >> 4, lm = lane & 15;
    const int lr = lane >> 3;
    const int lc = (lane & 7) * 8;
    f32x4 acc[4][4] = {};
    for (int k0 = 0; k0 < DM; k0 += 64) {
        __syncthreads();
        for (int j = 0; j < 4; j++) {
            int row = w * 32 + j * 8 + lr;
            async16(A  + (size_t)(m0 + row) * DM + k0 + lc, As + row * 64 + lc);
            async16(Bt + (size_t)(n0 + row) * DM + k0 + lc, Bs + row * 64 + lc);
        }
        __syncthreads();
        for (int ks = 0; ks < 64; ks += 32) {
            bf16x8 af[4], bfr[4];
            for (int i = 0; i < 4; i++) af[i]  = *(const bf16x8*)(As + (wm + i * 16 + lm) * 64 + ks + quad * 8);
            for (int j = 0; j < 4; j++) bfr[j] = *(const bf16x8*)(Bs + (wn + j * 16 + lm) * 64 + ks + quad * 8);
            for (int i = 0; i < 4; i++)
                for (int j = 0; j < 4; j++)
                    acc[i][j] = __builtin_amdgcn_mfma_f32_16x16x32_bf16(af[i], bfr[j], acc[i][j], 0, 0, 0);
        }
    }
    for (int i = 0; i < 4; i++)
        for (int j = 0; j < 4; j++)
            for (int r = 0; r < 4; r++) {
                int gm = m0 + wm + i * 16 + quad * 4 + r;
                int gn = n0 + wn + j * 16 + lm;
                C[(size_t)gm * NP + gn] = f2bf(acc[i][j][r]);
            }
}

// ---- 2: causal depthwise conv(4) + SiLU ----
__global__ void conv_silu_kernel(const u16* __restrict__ zx, const float* __restrict__ cw,
                                 const float* __restrict__ cb, u16* __restrict__ xbc) {
    int c = blockIdx.x * 256 + threadIdx.x;
    int row = blockIdx.y;
    int l = row & (L_SZ - 1);
    float acc = cb[c];
    for (int k = 0; k < DCV; k++) {
        int ls = l - 3 + k;
        if (ls >= 0) acc += bf2f(zx[(size_t)(row - 3 + k) * NP + DI + c]) * cw[c * DCV + k];
    }
    float s = acc / (1.f + expf(-acc));
    xbc[(size_t)row * CDIM + c] = f2bf(s);
}

// ---- 3: dt = softplus(raw+bias), per-chunk cumsum of dA ----
__global__ void dt_scan_kernel(const u16* __restrict__ zx, const float* __restrict__ dt_bias,
                               const float* __restrict__ A_log, float* __restrict__ dtb,
                               float* __restrict__ acs) {
    int bid = blockIdx.x;
    int h = bid & 63, c = (bid >> 6) & 7, b = bid >> 9;
    int t = threadIdx.x;
    int row = b * L_SZ + c * CH + t;
    float raw = bf2f(zx[(size_t)row * NP + (DI + CDIM) + h]) + dt_bias[h];
    float dtv = (raw > 20.f) ? raw : log1pf(expf(raw));
    float dA = dtv * (-expf(A_log[h]));
    dtb[row * NH + h] = dtv;
    __shared__ float sc[256];
    sc[t] = dA;
    for (int off = 1; off < 256; off <<= 1) {
        __syncthreads();
        float v = (t >= off) ? sc[t - off] : 0.f;
        __syncthreads();
        sc[t] += v;
    }
    acs[((size_t)((b * NH + h) * NCK + c)) * CH + t] = sc[t];
}

// ---- 4: G[t,s] = sum_n Cm[t,n]*Bm[s,n] per (b,c) ----
__global__ void g_kernel(const u16* __restrict__ xbc, float* __restrict__ G) {
    int blk = blockIdx.x;
    int bc = blk >> 4;
    int tile = blk & 15;
    int tb0 = (tile >> 2) * 64, sb0 = (tile & 3) * 64;
    int row0 = bc * CH;
    __shared__ float Ct[64][65], Bt_[64][65];
    int tq = (threadIdx.x >> 4) * 4;
    int sq = (threadIdx.x & 15) * 4;
    float acc[4][4] = {};
    for (int nh = 0; nh < 2; nh++) {
        __syncthreads();
        int r = threadIdx.x >> 2, cc = (threadIdx.x & 3) * 16;
        for (int q = 0; q < 16; q += 4) {
            ushort4 cv = *(const ushort4*)&xbc[(size_t)(row0 + tb0 + r) * CDIM + (DI + DS) + nh * 64 + cc + q];
            ushort4 bv = *(const ushort4*)&xbc[(size_t)(row0 + sb0 + r) * CDIM + DI + nh * 64 + cc + q];
            Ct[r][cc + q] = bf2f(cv.x); Ct[r][cc + q + 1] = bf2f(cv.y); Ct[r][cc + q + 2] = bf2f(cv.z); Ct[r][cc + q + 3] = bf2f(cv.w);
            Bt_[r][cc + q] = bf2f(bv.x); Bt_[r][cc + q + 1] = bf2f(bv.y); Bt_[r][cc + q + 2] = bf2f(bv.z); Bt_[r][cc + q + 3] = bf2f(bv.w);
        }
        __syncthreads();
        for (int n = 0; n < 64; n++) {
            float a[4], bb[4];
            for (int i = 0; i < 4; i++) a[i] = Ct[tq + i][n];
            for (int j = 0; j < 4; j++) bb[j] = Bt_[sq + j][n];
            for (int i = 0; i < 4; i++)
                for (int j = 0; j < 4; j++) acc[i][j] += a[i] * bb[j];
        }
    }
    for (int i = 0; i < 4; i++)
        for (int j = 0; j < 4; j++)
            G[((size_t)(row0 + tb0 + tq + i)) * CH + sb0 + sq + j] = acc[i][j];
}

// ---- 5: states[p,n] = sum_t Bm[t,n]*exp(Acs[255]-Acs[t])*xdt[t,p] per (b,c,h) ----
__global__ __launch_bounds__(256) void states_kernel(const u16* __restrict__ xbc, const float* __restrict__ dtb,
                                                     const float* __restrict__ acs_g, float* __restrict__ states) {
    int bid = blockIdx.x;
    int h = bid & 63, c = (bid >> 6) & 7, b = bid >> 9;
    int row0 = b * L_SZ + c * CH;
    const float* acs = acs_g + ((size_t)((b * NH + h) * NCK + c)) * CH;
    __shared__ float decay[256];
    __shared__ float Xs[32][64];
    __shared__ float Bs[32][128];
    int tid = threadIdx.x;
    decay[tid] = expf(acs[255] - acs[tid]);
    float acc[8][4] = {};
    int pb = (tid >> 5) * 8, nl = tid & 31;
    for (int t0 = 0; t0 < CH; t0 += 32) {
        __syncthreads();
        {
            int r = tid >> 3, cc = (tid & 7) * 8;
            int row = row0 + t0 + r;
            float dscale = dtb[row * NH + h] * decay[t0 + r];
            for (int q = 0; q < 8; q += 4) {
                ushort4 xv = *(const ushort4*)&xbc[(size_t)row * CDIM + h * HD + cc + q];
                Xs[r][cc + q] = bf2f(xv.x) * dscale; Xs[r][cc + q + 1] = bf2f(xv.y) * dscale;
                Xs[r][cc + q + 2] = bf2f(xv.z) * dscale; Xs[r][cc + q + 3] = bf2f(xv.w) * dscale;
            }
            int c2 = (tid & 7) * 16;
            for (int q = 0; q < 16; q += 4) {
                ushort4 bv = *(const ushort4*)&xbc[(size_t)row * CDIM + DI + c2 + q];
                Bs[r][c2 + q] = bf2f(bv.x); Bs[r][c2 + q + 1] = bf2f(bv.y);
                Bs[r][c2 + q + 2] = bf2f(bv.z); Bs[r][c2 + q + 3] = bf2f(bv.w);
            }
        }
        __syncthreads();
        for (int t = 0; t < 32; t++) {
            float xv[8], bv[4];
            for (int i = 0; i < 8; i++) xv[i] = Xs[t][pb + i];
            for (int j = 0; j < 4; j++) bv[j] = Bs[t][nl + 32 * j];
            for (int i = 0; i < 8; i++)
                for (int j = 0; j < 4; j++) acc[i][j] += xv[i] * bv[j];
        }
    }
    float* st = states + (size_t)bid * (HD * DS);
    for (int i = 0; i < 8; i++)
        for (int j = 0; j < 4; j++) st[(pb + i) * DS + nl + 32 * j] = acc[i][j];
}

// ---- 6: inter-chunk scan IN PLACE ----
__global__ void cscan_kernel(float* __restrict__ states, const float* __restrict__ acs_g) {
    int bid = blockIdx.x;
    int h = bid & 63, b = bid >> 6;
    int tid = threadIdx.x;
    float4 carry[8];
    for (int i = 0; i < 8; i++) carry[i] = make_float4(0.f, 0.f, 0.f, 0.f);
    for (int c = 0; c < NCK; c++) {
        size_t base = ((size_t)((b * NCK + c) * NH + h)) * (HD * DS);
        float g = expf(acs_g[((size_t)((b * NH + h) * NCK + c)) * CH + (CH - 1)]);
        float4* sp = (float4*)(states + base);
        for (int i = 0; i < 8; i++) {
            int idx = tid + 256 * i;
            float4 s = sp[idx];
            sp[idx] = carry[i];
            carry[i].x = carry[i].x * g + s.x;
            carry[i].y = carry[i].y * g + s.y;
            carry[i].z = carry[i].z * g + s.z;
            carry[i].w = carry[i].w * g + s.w;
        }
    }
}

// ---- 7: y = Yo + Yd + D_skip*x per (b,c,h) — MFMA version ----
// Yo = Cm(256x128) @ Ss^T(128x64), scaled per-row by exp(acs_t) AFTER accumulation
// Yd = M(256x256) @ Xdt(256x64), M[t,s] = G[t,s]*exp(acs_t - acs_s) for s<=t else 0
__global__ __launch_bounds__(256) void y_kernel(const u16* __restrict__ xbc, const float* __restrict__ dtb,
                                                const float* __restrict__ acs_g, const float* __restrict__ G,
                                                const float* __restrict__ init_st, const float* __restrict__ D_skip,
                                                u16* __restrict__ y) {
    int bid = blockIdx.x;                 // (b,c,h)
    int h = bid & 63, c = (bid >> 6) & 7, b = bid >> 9;
    int bc = b * NCK + c;
    int row0 = b * L_SZ + c * CH;
    int tid = threadIdx.x;
    int lane = tid & 63, w = tid >> 6;
    int wt = w * 64;                      // wave's 64-row t-range
    int quad = lane >> 4, lm = lane & 15;

    __shared__ float acs[CH];             // 1 KB
    __shared__ u16 Ssb[HD * DS];          // 16 KB  states bf16 [p][n]
    __shared__ u16 Ms[CH * 64];           // 32 KB  M chunk [t][s_local]
    __shared__ u16 XT[64 * 64];           // 8 KB   Xdt^T [p][s_local]

    acs[tid] = acs_g[((size_t)((b * NH + h) * NCK + c)) * CH + tid];
    {   // states f32 -> bf16 LDS
        const float4* sg = (const float4*)(init_st + ((size_t)(bc * NH + h)) * (HD * DS));
        for (int i = 0; i < 8; i++) {
            float4 v = sg[tid + 256 * i];
            ushort4 o;
            o.x = f2bf(v.x); o.y = f2bf(v.y); o.z = f2bf(v.z); o.w = f2bf(v.w);
            ((ushort4*)Ssb)[tid + 256 * i] = o;
        }
    }
    __syncthreads();

    f32x4 acc[4][4] = {};
    // ---- Yo: A-frag = raw Cm rows straight from global; B-frag = Ssb ----
    for (int i = 0; i < 4; i++) {
        const u16* arow = xbc + (size_t)(row0 + wt + i * 16 + lm) * CDIM + (DI + DS);
        for (int ks = 0; ks < 4; ks++) {            // K = 128
            bf16x8 af = *(const bf16x8*)(arow + ks * 32 + quad * 8);
            for (int j = 0; j < 4; j++) {
                bf16x8 bfr = *(const bf16x8*)(Ssb + (j * 16 + lm) * DS + ks * 32 + quad * 8);
                acc[i][j] = __builtin_amdgcn_mfma_f32_16x16x32_bf16(af, bfr, acc[i][j], 0, 0, 0);
            }
        }
    }
    // scale Yo rows by exp(acs_t); row of D = quad*4 + r within tile
    for (int i = 0; i < 4; i++) {
        float et[4];
        for (int r = 0; r < 4; r++) et[r] = expf(acs[wt + i * 16 + quad * 4 + r]);
        for (int j = 0; j < 4; j++)
            for (int r = 0; r < 4; r++) acc[i][j][r] *= et[r];
    }

    // ---- Yd: 4 chunks of 64 along s ----
    const float* gbase = G + (size_t)bc * CH * CH;
    for (int s0 = 0; s0 < CH; s0 += 64) {
        __syncthreads();    // prev chunk's MFMA reads done before overwrite
        {   // build Ms: lane -> s_local (coalesced G reads, conflict-free LDS writes)
            int sl = tid & 63;
            int tb = (tid >> 6) * 64;
            int sg = s0 + sl;
            float as = acs[sg];
            for (int i = 0; i < 64; i++) {
                int t = tb + i;
                float m = 0.f;
                if (sg <= t) m = gbase[(size_t)t * CH + sg] * expf(acs[t] - as);
                Ms[t * 64 + sl] = f2bf(m);
            }
        }
        {   // build XT[p][s]: Xdt transposed
            int r = tid >> 2;               // s row 0..63
            int cseg = (tid & 3) * 16;      // p segment
            int row = row0 + s0 + r;
            float dv = dtb[row * NH + h];
            const u16* xr = xbc + (size_t)row * CDIM + h * HD + cseg;
            for (int q = 0; q < 16; q += 4) {
                ushort4 xv = *(const ushort4*)(xr + q);
                XT[(cseg + q + 0) * 64 + r] = f2bf(bf2f(xv.x) * dv);
                XT[(cseg + q + 1) * 64 + r] = f2bf(bf2f(xv.y) * dv);
                XT[(cseg + q + 2) * 64 + r] = f2bf(bf2f(xv.z) * dv);
                XT[(cseg + q + 3) * 64 + r] = f2bf(bf2f(xv.w) * dv);
            }
        }
        __syncthreads();
        if (wt + 63 >= s0) {                // triangular wave-level skip
            for (int i = 0; i < 4; i++) {
                if (wt + i * 16 + 15 < s0) continue;   // tile fully above diagonal
                for (int ks = 0; ks < 2; ks++) {
                    bf16x8 af = *(const bf16x8*)(Ms + (wt + i * 16 + lm) * 64 + ks * 32 + quad * 8);
                    for (int j = 0; j < 4; j++) {
                        bf16x8 bfr = *(const bf16x8*)(XT + (j * 16 + lm) * 64 + ks * 32 + quad * 8);
                        acc[i][j] = __builtin_amdgcn_mfma_f32_16x16x32_bf16(af, bfr, acc[i][j], 0, 0, 0);
                    }
                }
            }
        }
    }

    // ---- epilogue: + D_skip * x, store bf16 ----
    float dsk = D_skip[h];
    for (int i = 0; i < 4; i++)
        for (int r = 0; r < 4; r++) {
            int grow = row0 + wt + i * 16 + quad * 4 + r;
            const u16* xrow = xbc + (size_t)grow * CDIM + h * HD;
            u16* yrow = y + (size_t)grow * DI + h * HD;
            for (int j = 0; j < 4; j++) {
                int p = j * 16 + lm;
                yrow[p] = f2bf(acc[i][j][r] + dsk * bf2f(xrow[p]));
            }
        }
}

// ---- 8: out = (y * silu(z)) * rsqrt(mean(yg^2)+eps) * norm_w ----
__global__ void final_kernel(const u16* __restrict__ y, const u16* __restrict__ zx,
                             const float* __restrict__ norm_w, float* __restrict__ out) {
    int row = blockIdx.x;
    int tid = threadIdx.x;
    __shared__ float red[4];
    float yg[16];
    float ss = 0.f;
    for (int i = 0; i < 16; i++) {
        int col = tid + 256 * i;
        float z = bf2f(zx[(size_t)row * NP + col]);
        float g = bf2f(y[(size_t)row * DI + col]) * (z / (1.f + expf(-z)));
        yg[i] = g; ss += g * g;
    }
    for (int off = 32; off; off >>= 1) ss += __shfl_down(ss, off);
    if ((tid & 63) == 0) red[tid >> 6] = ss;
    __syncthreads();
    if (tid == 0) red[0] = red[0] + red[1] + red[2] + red[3];
    __syncthreads();
    float inv = rsqrtf(red[0] / (float)DI + 1e-5f);
    for (int i = 0; i < 16; i++) {
        int col = tid + 256 * i;
        out[(size_t)row * DI + col] = yg[i] * inv * norm_w[col];
    }
}

extern "C" void kernel_launch(void* const* d_in, const int* in_sizes, int n_in,
                              void* d_out, int out_size, void* d_ws, size_t ws_size,
                              hipStream_t stream) {
    const float* u       = (const float*)d_in[0];
    const float* w_in    = (const float*)d_in[1];
    const float* conv_w  = (const float*)d_in[2];
    const float* conv_b  = (const float*)d_in[3];
    const float* dt_bias = (const float*)d_in[4];
    const float* A_log   = (const float*)d_in[5];
    const float* D_skip  = (const float*)d_in[6];
    const float* norm_w  = (const float*)d_in[7];
    float* out = (float*)d_out;

    const size_t NEEDED = 179306496ull;
    if (ws_size < NEEDED) return;

    char* ws = (char*)d_ws;
    const size_t R = 70254592ull;
    u16*   zx   = (u16*)ws;
    u16*   ubf  = (u16*)(ws + R);
    u16*   wtb  = (u16*)(ws + R + 16777216);
    u16*   xbc  = (u16*)(ws + R);
    float* dtb  = (float*)(ws + R + 35651584);
    float* acs  = (float*)(ws + R + 36700160);
    float* G    = (float*)(ws + R + 37748736);
    float* stat = (float*)(ws + R + 41943040);
    u16*   yb   = (u16*)(ws + R + 75497472);

    cvt_u_kernel<<<8192, 256, 0, stream>>>(u, ubf);
    transpose_w_kernel<<<dim3(268, 64), 256, 0, stream>>>(w_in, wtb);
    gemm_kernel<<<GEMM_NM * GEMM_NN, 256, 0, stream>>>(ubf, wtb, zx);
    conv_silu_kernel<<<dim3(17, 4096), 256, 0, stream>>>(zx, conv_w, conv_b, xbc);
    dt_scan_kernel<<<1024, 256, 0, stream>>>(zx, dt_bias, A_log, dtb, acs);
    g_kernel<<<256, 256, 0, stream>>>(xbc, G);
    states_kernel<<<1024, 256, 0, stream>>>(xbc, dtb, acs, stat);
    cscan_kernel<<<128, 256, 0, stream>>>(stat, acs);
    y_kernel<<<1024, 256, 0, stream>>>(xbc, dtb, acs, G, stat, D_skip, yb);
    final_kernel<<<4096, 256, 0, stream>>>(yb, zx, norm_w, out);
}

// Round 6
// 701.690 us; speedup vs baseline: 2.0243x; 1.0420x over previous
//
#include <hip/hip_runtime.h>
#include <hip/hip_bf16.h>

// ---- problem constants ----
#define B_SZ   2
#define L_SZ   2048
#define DM     2048
#define DS     128
#define DCV    4
#define HD     64
#define CH     256
#define DI     4096
#define NH     64
#define DIP    8512
#define CDIM   4352
#define NP     8576      // DIP padded to 67*128
#define MROWS  4096      // B_SZ*L_SZ
#define NCK    8         // L_SZ/CH

typedef __attribute__((ext_vector_type(8))) short bf16x8;
typedef __attribute__((ext_vector_type(4))) float f32x4;
typedef unsigned short u16;

__device__ __forceinline__ u16 f2bf(float f) {
    union { float f; unsigned u; } c; c.f = f;
    unsigned r = c.u + 0x7fffu + ((c.u >> 16) & 1u);
    return (u16)(r >> 16);
}
__device__ __forceinline__ float bf2f(u16 b) {
    union { unsigned u; float f; } c; c.u = ((unsigned)b) << 16; return c.f;
}

// async global->LDS copy, 16 B per lane (global_load_lds_dwordx4)
__device__ __forceinline__ void async16(const u16* g, u16* l) {
    __builtin_amdgcn_global_load_lds(
        (const __attribute__((address_space(1))) unsigned int*)(g),
        (__attribute__((address_space(3))) unsigned int*)(l),
        16, 0, 0);
}

// ---- 0a: u f32 -> bf16 ----
__global__ void cvt_u_kernel(const float* __restrict__ u, u16* __restrict__ ub) {
    int i = blockIdx.x * 256 + threadIdx.x;
    float4 v = ((const float4*)u)[i];
    ushort4 o;
    o.x = f2bf(v.x); o.y = f2bf(v.y); o.z = f2bf(v.z); o.w = f2bf(v.w);
    ((ushort4*)ub)[i] = o;
}

// ---- 0b: w_in (K=2048 x DIP) f32 -> w_inT (NP x K) bf16, zero-pad rows >= DIP ----
__global__ void transpose_w_kernel(const float* __restrict__ w, u16* __restrict__ wt) {
    __shared__ float tile[32][33];
    int n0 = blockIdx.x * 32, k0 = blockIdx.y * 32;
    int tx = threadIdx.x & 31, ty = threadIdx.x >> 5;
    for (int j = 0; j < 32; j += 8) {
        int k = k0 + ty + j, n = n0 + tx;
        tile[ty + j][tx] = (n < DIP) ? w[(size_t)k * DIP + n] : 0.f;
    }
    __syncthreads();
    for (int j = 0; j < 32; j += 8) {
        int n = n0 + ty + j, k = k0 + tx;
        wt[(size_t)n * DM + k] = f2bf(tile[tx][ty + j]);
    }
}

// ---- 1: GEMM zxbcdt = u @ w_in -> bf16 [MROWS][NP]
// m97 structure + grouped-M swizzle + XOR bank swizzle (chunk ^= row&7) ----
#define GEMM_NM 32
#define GEMM_NN 67
#define GEMM_GM 8
__global__ __launch_bounds__(256) void gemm_kernel(const u16* __restrict__ A,
                                                   const u16* __restrict__ Bt,
                                                   u16* __restrict__ C) {
    __shared__ u16 As[128 * 64];
    __shared__ u16 Bs[128 * 64];
    const int bid = blockIdx.x;
    const int width = GEMM_GM * GEMM_NN;
    const int group = bid / width;
    const int rem = bid - group * width;
    const int pid_m = group * GEMM_GM + (rem % GEMM_GM);
    const int pid_n = rem / GEMM_GM;
    const int m0 = pid_m * 128, n0 = pid_n * 128;

    const int tid = threadIdx.x;
    const int lane = tid & 63, w = tid >> 6;
    const int wm = (w >> 1) * 64, wn = (w & 1) * 64;
    const int quad = lane >> 4, lm = lane & 15;
    const int lr = lane >> 3;            // row within 8-row stripe
    const int pc = lane & 7;             // physical 16B chunk within row
    const int lcl = ((pc ^ lr) * 8);     // swizzled logical col (u16) to fetch
    const int sx = (lm & 7);             // read-side swizzle key
    f32x4 acc[4][4] = {};
    for (int k0 = 0; k0 < DM; k0 += 64) {
        __syncthreads();
        for (int j = 0; j < 4; j++) {
            int row = w * 32 + j * 8 + lr;
            // dest offset row*64 + pc*8 == stripe_base + lane*8 u16 (contiguous lane order)
            async16(A  + (size_t)(m0 + row) * DM + k0 + lcl, As + row * 64 + pc * 8);
            async16(Bt + (size_t)(n0 + row) * DM + k0 + lcl, Bs + row * 64 + pc * 8);
        }
        __syncthreads();
        for (int half = 0; half < 2; half++) {
            int cq = half * 4 + quad;            // logical chunk for this fragment
            int co = (cq ^ sx) * 8;              // physical (swizzled) offset
            bf16x8 af[4], bfr[4];
            for (int i = 0; i < 4; i++) af[i]  = *(const bf16x8*)(As + (wm + i * 16 + lm) * 64 + co);
            for (int j = 0; j < 4; j++) bfr[j] = *(const bf16x8*)(Bs + (wn + j * 16 + lm) * 64 + co);
            for (int i = 0; i < 4; i++)
                for (int j = 0; j < 4; j++)
                    acc[i][j] = __builtin_amdgcn_mfma_f32_16x16x32_bf16(af[i], bfr[j], acc[i][j], 0, 0, 0);
        }
    }
    for (int i = 0; i < 4; i++)
        for (int j = 0; j < 4; j++)
            for (int r = 0; r < 4; r++) {
                int gm = m0 + wm + i * 16 + quad * 4 + r;
                int gn = n0 + wn + j * 16 + lm;
                C[(size_t)gm * NP + gn] = f2bf(acc[i][j][r]);
            }
}

// ---- 2: causal depthwise conv(4) + SiLU ----
__global__ void conv_silu_kernel(const u16* __restrict__ zx, const float* __restrict__ cw,
                                 const float* __restrict__ cb, u16* __restrict__ xbc) {
    int c = blockIdx.x * 256 + threadIdx.x;
    int row = blockIdx.y;
    int l = row & (L_SZ - 1);
    float acc = cb[c];
    for (int k = 0; k < DCV; k++) {
        int ls = l - 3 + k;
        if (ls >= 0) acc += bf2f(zx[(size_t)(row - 3 + k) * NP + DI + c]) * cw[c * DCV + k];
    }
    float s = acc / (1.f + expf(-acc));
    xbc[(size_t)row * CDIM + c] = f2bf(s);
}

// ---- 3: dt = softplus(raw+bias), per-chunk cumsum of dA ----
__global__ void dt_scan_kernel(const u16* __restrict__ zx, const float* __restrict__ dt_bias,
                               const float* __restrict__ A_log, float* __restrict__ dtb,
                               float* __restrict__ acs) {
    int bid = blockIdx.x;
    int h = bid & 63, c = (bid >> 6) & 7, b = bid >> 9;
    int t = threadIdx.x;
    int row = b * L_SZ + c * CH + t;
    float raw = bf2f(zx[(size_t)row * NP + (DI + CDIM) + h]) + dt_bias[h];
    float dtv = (raw > 20.f) ? raw : log1pf(expf(raw));
    float dA = dtv * (-expf(A_log[h]));
    dtb[row * NH + h] = dtv;
    __shared__ float sc[256];
    sc[t] = dA;
    for (int off = 1; off < 256; off <<= 1) {
        __syncthreads();
        float v = (t >= off) ? sc[t - off] : 0.f;
        __syncthreads();
        sc[t] += v;
    }
    acs[((size_t)((b * NH + h) * NCK + c)) * CH + t] = sc[t];
}

// ---- 4: G[t,s] = sum_n Cm[t,n]*Bm[s,n] per (b,c) ----
__global__ void g_kernel(const u16* __restrict__ xbc, float* __restrict__ G) {
    int blk = blockIdx.x;
    int bc = blk >> 4;
    int tile = blk & 15;
    int tb0 = (tile >> 2) * 64, sb0 = (tile & 3) * 64;
    int row0 = bc * CH;
    __shared__ float Ct[64][65], Bt_[64][65];
    int tq = (threadIdx.x >> 4) * 4;
    int sq = (threadIdx.x & 15) * 4;
    float acc[4][4] = {};
    for (int nh = 0; nh < 2; nh++) {
        __syncthreads();
        int r = threadIdx.x >> 2, cc = (threadIdx.x & 3) * 16;
        for (int q = 0; q < 16; q += 4) {
            ushort4 cv = *(const ushort4*)&xbc[(size_t)(row0 + tb0 + r) * CDIM + (DI + DS) + nh * 64 + cc + q];
            ushort4 bv = *(const ushort4*)&xbc[(size_t)(row0 + sb0 + r) * CDIM + DI + nh * 64 + cc + q];
            Ct[r][cc + q] = bf2f(cv.x); Ct[r][cc + q + 1] = bf2f(cv.y); Ct[r][cc + q + 2] = bf2f(cv.z); Ct[r][cc + q + 3] = bf2f(cv.w);
            Bt_[r][cc + q] = bf2f(bv.x); Bt_[r][cc + q + 1] = bf2f(bv.y); Bt_[r][cc + q + 2] = bf2f(bv.z); Bt_[r][cc + q + 3] = bf2f(bv.w);
        }
        __syncthreads();
        for (int n = 0; n < 64; n++) {
            float a[4], bb[4];
            for (int i = 0; i < 4; i++) a[i] = Ct[tq + i][n];
            for (int j = 0; j < 4; j++) bb[j] = Bt_[sq + j][n];
            for (int i = 0; i < 4; i++)
                for (int j = 0; j < 4; j++) acc[i][j] += a[i] * bb[j];
        }
    }
    for (int i = 0; i < 4; i++)
        for (int j = 0; j < 4; j++)
            G[((size_t)(row0 + tb0 + tq + i)) * CH + sb0 + sq + j] = acc[i][j];
}

// ---- 5: states[p,n] = sum_t Bm[t,n]*exp(Acs[255]-Acs[t])*xdt[t,p] per (b,c,h) ----
__global__ __launch_bounds__(256) void states_kernel(const u16* __restrict__ xbc, const float* __restrict__ dtb,
                                                     const float* __restrict__ acs_g, float* __restrict__ states) {
    int bid = blockIdx.x;
    int h = bid & 63, c = (bid >> 6) & 7, b = bid >> 9;
    int row0 = b * L_SZ + c * CH;
    const float* acs = acs_g + ((size_t)((b * NH + h) * NCK + c)) * CH;
    __shared__ float decay[256];
    __shared__ float Xs[32][64];
    __shared__ float Bs[32][128];
    int tid = threadIdx.x;
    decay[tid] = expf(acs[255] - acs[tid]);
    float acc[8][4] = {};
    int pb = (tid >> 5) * 8, nl = tid & 31;
    for (int t0 = 0; t0 < CH; t0 += 32) {
        __syncthreads();
        {
            int r = tid >> 3, cc = (tid & 7) * 8;
            int row = row0 + t0 + r;
            float dscale = dtb[row * NH + h] * decay[t0 + r];
            for (int q = 0; q < 8; q += 4) {
                ushort4 xv = *(const ushort4*)&xbc[(size_t)row * CDIM + h * HD + cc + q];
                Xs[r][cc + q] = bf2f(xv.x) * dscale; Xs[r][cc + q + 1] = bf2f(xv.y) * dscale;
                Xs[r][cc + q + 2] = bf2f(xv.z) * dscale; Xs[r][cc + q + 3] = bf2f(xv.w) * dscale;
            }
            int c2 = (tid & 7) * 16;
            for (int q = 0; q < 16; q += 4) {
                ushort4 bv = *(const ushort4*)&xbc[(size_t)row * CDIM + DI + c2 + q];
                Bs[r][c2 + q] = bf2f(bv.x); Bs[r][c2 + q + 1] = bf2f(bv.y);
                Bs[r][c2 + q + 2] = bf2f(bv.z); Bs[r][c2 + q + 3] = bf2f(bv.w);
            }
        }
        __syncthreads();
        for (int t = 0; t < 32; t++) {
            float xv[8], bv[4];
            for (int i = 0; i < 8; i++) xv[i] = Xs[t][pb + i];
            for (int j = 0; j < 4; j++) bv[j] = Bs[t][nl + 32 * j];
            for (int i = 0; i < 8; i++)
                for (int j = 0; j < 4; j++) acc[i][j] += xv[i] * bv[j];
        }
    }
    float* st = states + (size_t)bid * (HD * DS);
    for (int i = 0; i < 8; i++)
        for (int j = 0; j < 4; j++) st[(pb + i) * DS + nl + 32 * j] = acc[i][j];
}

// ---- 6: inter-chunk scan IN PLACE ----
__global__ void cscan_kernel(float* __restrict__ states, const float* __restrict__ acs_g) {
    int bid = blockIdx.x;
    int h = bid & 63, b = bid >> 6;
    int tid = threadIdx.x;
    float4 carry[8];
    for (int i = 0; i < 8; i++) carry[i] = make_float4(0.f, 0.f, 0.f, 0.f);
    for (int c = 0; c < NCK; c++) {
        size_t base = ((size_t)((b * NCK + c) * NH + h)) * (HD * DS);
        float g = expf(acs_g[((size_t)((b * NH + h) * NCK + c)) * CH + (CH - 1)]);
        float4* sp = (float4*)(states + base);
        for (int i = 0; i < 8; i++) {
            int idx = tid + 256 * i;
            float4 s = sp[idx];
            sp[idx] = carry[i];
            carry[i].x = carry[i].x * g + s.x;
            carry[i].y = carry[i].y * g + s.y;
            carry[i].z = carry[i].z * g + s.z;
            carry[i].w = carry[i].w * g + s.w;
        }
    }
}

// ---- 7: y = Yo + Yd + D_skip*x per (b,c,h) — MFMA version ----
__global__ __launch_bounds__(256) void y_kernel(const u16* __restrict__ xbc, const float* __restrict__ dtb,
                                                const float* __restrict__ acs_g, const float* __restrict__ G,
                                                const float* __restrict__ init_st, const float* __restrict__ D_skip,
                                                u16* __restrict__ y) {
    int bid = blockIdx.x;                 // (b,c,h)
    int h = bid & 63, c = (bid >> 6) & 7, b = bid >> 9;
    int bc = b * NCK + c;
    int row0 = b * L_SZ + c * CH;
    int tid = threadIdx.x;
    int lane = tid & 63, w = tid >> 6;
    int wt = w * 64;
    int quad = lane >> 4, lm = lane & 15;

    __shared__ float acs[CH];
    __shared__ u16 Ssb[HD * DS];
    __shared__ u16 Ms[CH * 64];
    __shared__ u16 XT[64 * 64];

    acs[tid] = acs_g[((size_t)((b * NH + h) * NCK + c)) * CH + tid];
    {
        const float4* sg = (const float4*)(init_st + ((size_t)(bc * NH + h)) * (HD * DS));
        for (int i = 0; i < 8; i++) {
            float4 v = sg[tid + 256 * i];
            ushort4 o;
            o.x = f2bf(v.x); o.y = f2bf(v.y); o.z = f2bf(v.z); o.w = f2bf(v.w);
            ((ushort4*)Ssb)[tid + 256 * i] = o;
        }
    }
    __syncthreads();

    f32x4 acc[4][4] = {};
    for (int i = 0; i < 4; i++) {
        const u16* arow = xbc + (size_t)(row0 + wt + i * 16 + lm) * CDIM + (DI + DS);
        for (int ks = 0; ks < 4; ks++) {
            bf16x8 af = *(const bf16x8*)(arow + ks * 32 + quad * 8);
            for (int j = 0; j < 4; j++) {
                bf16x8 bfr = *(const bf16x8*)(Ssb + (j * 16 + lm) * DS + ks * 32 + quad * 8);
                acc[i][j] = __builtin_amdgcn_mfma_f32_16x16x32_bf16(af, bfr, acc[i][j], 0, 0, 0);
            }
        }
    }
    for (int i = 0; i < 4; i++) {
        float et[4];
        for (int r = 0; r < 4; r++) et[r] = expf(acs[wt + i * 16 + quad * 4 + r]);
        for (int j = 0; j < 4; j++)
            for (int r = 0; r < 4; r++) acc[i][j][r] *= et[r];
    }

    const float* gbase = G + (size_t)bc * CH * CH;
    for (int s0 = 0; s0 < CH; s0 += 64) {
        __syncthreads();
        {
            int sl = tid & 63;
            int tb = (tid >> 6) * 64;
            int sg = s0 + sl;
            float as = acs[sg];
            for (int i = 0; i < 64; i++) {
                int t = tb + i;
                float m = 0.f;
                if (sg <= t) m = gbase[(size_t)t * CH + sg] * expf(acs[t] - as);
                Ms[t * 64 + sl] = f2bf(m);
            }
        }
        {
            int r = tid >> 2;
            int cseg = (tid & 3) * 16;
            int row = row0 + s0 + r;
            float dv = dtb[row * NH + h];
            const u16* xr = xbc + (size_t)row * CDIM + h * HD + cseg;
            for (int q = 0; q < 16; q += 4) {
                ushort4 xv = *(const ushort4*)(xr + q);
                XT[(cseg + q + 0) * 64 + r] = f2bf(bf2f(xv.x) * dv);
                XT[(cseg + q + 1) * 64 + r] = f2bf(bf2f(xv.y) * dv);
                XT[(cseg + q + 2) * 64 + r] = f2bf(bf2f(xv.z) * dv);
                XT[(cseg + q + 3) * 64 + r] = f2bf(bf2f(xv.w) * dv);
            }
        }
        __syncthreads();
        if (wt + 63 >= s0) {
            for (int i = 0; i < 4; i++) {
                if (wt + i * 16 + 15 < s0) continue;
                for (int ks = 0; ks < 2; ks++) {
                    bf16x8 af = *(const bf16x8*)(Ms + (wt + i * 16 + lm) * 64 + ks * 32 + quad * 8);
                    for (int j = 0; j < 4; j++) {
                        bf16x8 bfr = *(const bf16x8*)(XT + (j * 16 + lm) * 64 + ks * 32 + quad * 8);
                        acc[i][j] = __builtin_amdgcn_mfma_f32_16x16x32_bf16(af, bfr, acc[i][j], 0, 0, 0);
                    }
                }
            }
        }
    }

    float dsk = D_skip[h];
    for (int i = 0; i < 4; i++)
        for (int r = 0; r < 4; r++) {
            int grow = row0 + wt + i * 16 + quad * 4 + r;
            const u16* xrow = xbc + (size_t)grow * CDIM + h * HD;
            u16* yrow = y + (size_t)grow * DI + h * HD;
            for (int j = 0; j < 4; j++) {
                int p = j * 16 + lm;
                yrow[p] = f2bf(acc[i][j][r] + dsk * bf2f(xrow[p]));
            }
        }
}

// ---- 8: out = (y * silu(z)) * rsqrt(mean(yg^2)+eps) * norm_w ----
__global__ void final_kernel(const u16* __restrict__ y, const u16* __restrict__ zx,
                             const float* __restrict__ norm_w, float* __restrict__ out) {
    int row = blockIdx.x;
    int tid = threadIdx.x;
    __shared__ float red[4];
    float yg[16];
    float ss = 0.f;
    for (int i = 0; i < 16; i++) {
        int col = tid + 256 * i;
        float z = bf2f(zx[(size_t)row * NP + col]);
        float g = bf2f(y[(size_t)row * DI + col]) * (z / (1.f + expf(-z)));
        yg[i] = g; ss += g * g;
    }
    for (int off = 32; off; off >>= 1) ss += __shfl_down(ss, off);
    if ((tid & 63) == 0) red[tid >> 6] = ss;
    __syncthreads();
    if (tid == 0) red[0] = red[0] + red[1] + red[2] + red[3];
    __syncthreads();
    float inv = rsqrtf(red[0] / (float)DI + 1e-5f);
    for (int i = 0; i < 16; i++) {
        int col = tid + 256 * i;
        out[(size_t)row * DI + col] = yg[i] * inv * norm_w[col];
    }
}

extern "C" void kernel_launch(void* const* d_in, const int* in_sizes, int n_in,
                              void* d_out, int out_size, void* d_ws, size_t ws_size,
                              hipStream_t stream) {
    const float* u       = (const float*)d_in[0];
    const float* w_in    = (const float*)d_in[1];
    const float* conv_w  = (const float*)d_in[2];
    const float* conv_b  = (const float*)d_in[3];
    const float* dt_bias = (const float*)d_in[4];
    const float* A_log   = (const float*)d_in[5];
    const float* D_skip  = (const float*)d_in[6];
    const float* norm_w  = (const float*)d_in[7];
    float* out = (float*)d_out;

    const size_t NEEDED = 179306496ull;
    if (ws_size < NEEDED) return;

    char* ws = (char*)d_ws;
    const size_t R = 70254592ull;
    u16*   zx   = (u16*)ws;
    u16*   ubf  = (u16*)(ws + R);
    u16*   wtb  = (u16*)(ws + R + 16777216);
    u16*   xbc  = (u16*)(ws + R);
    float* dtb  = (float*)(ws + R + 35651584);
    float* acs  = (float*)(ws + R + 36700160);
    float* G    = (float*)(ws + R + 37748736);
    float* stat = (float*)(ws + R + 41943040);
    u16*   yb   = (u16*)(ws + R + 75497472);

    cvt_u_kernel<<<8192, 256, 0, stream>>>(u, ubf);
    transpose_w_kernel<<<dim3(268, 64), 256, 0, stream>>>(w_in, wtb);
    gemm_kernel<<<GEMM_NM * GEMM_NN, 256, 0, stream>>>(ubf, wtb, zx);
    conv_silu_kernel<<<dim3(17, 4096), 256, 0, stream>>>(zx, conv_w, conv_b, xbc);
    dt_scan_kernel<<<1024, 256, 0, stream>>>(zx, dt_bias, A_log, dtb, acs);
    g_kernel<<<256, 256, 0, stream>>>(xbc, G);
    states_kernel<<<1024, 256, 0, stream>>>(xbc, dtb, acs, stat);
    cscan_kernel<<<128, 256, 0, stream>>>(stat, acs);
    y_kernel<<<1024, 256, 0, stream>>>(xbc, dtb, acs, G, stat, D_skip, yb);
    final_kernel<<<4096, 256, 0, stream>>>(yb, zx, norm_w, out);
}

// Round 8
// 563.719 us; speedup vs baseline: 2.5197x; 1.2448x over previous
//
#include <hip/hip_runtime.h>
#include <hip/hip_bf16.h>

// ---- problem constants ----
#define B_SZ   2
#define L_SZ   2048
#define DM     2048
#define DS     128
#define DCV    4
#define HD     64
#define CH     256
#define DI     4096
#define NH     64
#define DIP    8512
#define CDIM   4352
#define NP     8576      // DIP padded to 67*128
#define MROWS  4096      // B_SZ*L_SZ
#define NCK    8         // L_SZ/CH

typedef __attribute__((ext_vector_type(8))) short bf16x8;
typedef __attribute__((ext_vector_type(4))) float f32x4;
typedef unsigned short u16;

__device__ __forceinline__ u16 f2bf(float f) {
    union { float f; unsigned u; } c; c.f = f;
    unsigned r = c.u + 0x7fffu + ((c.u >> 16) & 1u);
    return (u16)(r >> 16);
}
__device__ __forceinline__ float bf2f(u16 b) {
    union { unsigned u; float f; } c; c.u = ((unsigned)b) << 16; return c.f;
}

// async global->LDS copy, 16 B per lane (global_load_lds_dwordx4)
__device__ __forceinline__ void async16(const u16* g, u16* l) {
    __builtin_amdgcn_global_load_lds(
        (const __attribute__((address_space(1))) unsigned int*)(g),
        (__attribute__((address_space(3))) unsigned int*)(l),
        16, 0, 0);
}

// ---- 0a: u f32 -> bf16 ----
__global__ void cvt_u_kernel(const float* __restrict__ u, u16* __restrict__ ub) {
    int i = blockIdx.x * 256 + threadIdx.x;
    float4 v = ((const float4*)u)[i];
    ushort4 o;
    o.x = f2bf(v.x); o.y = f2bf(v.y); o.z = f2bf(v.z); o.w = f2bf(v.w);
    ((ushort4*)ub)[i] = o;
}

// ---- 0b: w_in (K=2048 x DIP) f32 -> w_inT (NP x K) bf16, zero-pad rows >= DIP ----
__global__ void transpose_w_kernel(const float* __restrict__ w, u16* __restrict__ wt) {
    __shared__ float tile[32][33];
    int n0 = blockIdx.x * 32, k0 = blockIdx.y * 32;
    int tx = threadIdx.x & 31, ty = threadIdx.x >> 5;
    for (int j = 0; j < 32; j += 8) {
        int k = k0 + ty + j, n = n0 + tx;
        tile[ty + j][tx] = (n < DIP) ? w[(size_t)k * DIP + n] : 0.f;
    }
    __syncthreads();
    for (int j = 0; j < 32; j += 8) {
        int n = n0 + ty + j, k = k0 + tx;
        wt[(size_t)n * DM + k] = f2bf(tile[tx][ty + j]);
    }
}

// ---- 1: GEMM zxbcdt = u @ w_in -> bf16 [MROWS][NP] (m97 + grouped-M + XOR swizzle) ----
#define GEMM_NM 32
#define GEMM_NN 67
#define GEMM_GM 8
__global__ __launch_bounds__(256) void gemm_kernel(const u16* __restrict__ A,
                                                   const u16* __restrict__ Bt,
                                                   u16* __restrict__ C) {
    __shared__ u16 As[128 * 64];
    __shared__ u16 Bs[128 * 64];
    const int bid = blockIdx.x;
    const int width = GEMM_GM * GEMM_NN;
    const int group = bid / width;
    const int rem = bid - group * width;
    const int pid_m = group * GEMM_GM + (rem % GEMM_GM);
    const int pid_n = rem / GEMM_GM;
    const int m0 = pid_m * 128, n0 = pid_n * 128;

    const int tid = threadIdx.x;
    const int lane = tid & 63, w = tid >> 6;
    const int wm = (w >> 1) * 64, wn = (w & 1) * 64;
    const int quad = lane >> 4, lm = lane & 15;
    const int lr = lane >> 3;
    const int pc = lane & 7;
    const int lcl = ((pc ^ lr) * 8);
    const int sx = (lm & 7);
    f32x4 acc[4][4] = {};
    for (int k0 = 0; k0 < DM; k0 += 64) {
        __syncthreads();
        for (int j = 0; j < 4; j++) {
            int row = w * 32 + j * 8 + lr;
            async16(A  + (size_t)(m0 + row) * DM + k0 + lcl, As + row * 64 + pc * 8);
            async16(Bt + (size_t)(n0 + row) * DM + k0 + lcl, Bs + row * 64 + pc * 8);
        }
        __syncthreads();
        for (int half = 0; half < 2; half++) {
            int cq = half * 4 + quad;
            int co = (cq ^ sx) * 8;
            bf16x8 af[4], bfr[4];
            for (int i = 0; i < 4; i++) af[i]  = *(const bf16x8*)(As + (wm + i * 16 + lm) * 64 + co);
            for (int j = 0; j < 4; j++) bfr[j] = *(const bf16x8*)(Bs + (wn + j * 16 + lm) * 64 + co);
            for (int i = 0; i < 4; i++)
                for (int j = 0; j < 4; j++)
                    acc[i][j] = __builtin_amdgcn_mfma_f32_16x16x32_bf16(af[i], bfr[j], acc[i][j], 0, 0, 0);
        }
    }
    for (int i = 0; i < 4; i++)
        for (int j = 0; j < 4; j++)
            for (int r = 0; r < 4; r++) {
                int gm = m0 + wm + i * 16 + quad * 4 + r;
                int gn = n0 + wn + j * 16 + lm;
                C[(size_t)gm * NP + gn] = f2bf(acc[i][j][r]);
            }
}

// ---- 2: causal depthwise conv(4) + SiLU ----
__global__ void conv_silu_kernel(const u16* __restrict__ zx, const float* __restrict__ cw,
                                 const float* __restrict__ cb, u16* __restrict__ xbc) {
    int c = blockIdx.x * 256 + threadIdx.x;
    int row = blockIdx.y;
    int l = row & (L_SZ - 1);
    float acc = cb[c];
    for (int k = 0; k < DCV; k++) {
        int ls = l - 3 + k;
        if (ls >= 0) acc += bf2f(zx[(size_t)(row - 3 + k) * NP + DI + c]) * cw[c * DCV + k];
    }
    float s = acc / (1.f + expf(-acc));
    xbc[(size_t)row * CDIM + c] = f2bf(s);
}

// ---- 3: dt = softplus(raw+bias) -> dtbT[h][row]; per-chunk cumsum of dA -> acs ----
__global__ void dt_scan_kernel(const u16* __restrict__ zx, const float* __restrict__ dt_bias,
                               const float* __restrict__ A_log, float* __restrict__ dtbT,
                               float* __restrict__ acs) {
    int bid = blockIdx.x;
    int h = bid & 63, c = (bid >> 6) & 7, b = bid >> 9;
    int t = threadIdx.x;
    int row = b * L_SZ + c * CH + t;
    float raw = bf2f(zx[(size_t)row * NP + (DI + CDIM) + h]) + dt_bias[h];
    float dtv = (raw > 20.f) ? raw : log1pf(expf(raw));
    float dA = dtv * (-expf(A_log[h]));
    dtbT[(size_t)h * MROWS + row] = dtv;
    __shared__ float sc[256];
    sc[t] = dA;
    for (int off = 1; off < 256; off <<= 1) {
        __syncthreads();
        float v = (t >= off) ? sc[t - off] : 0.f;
        __syncthreads();
        sc[t] += v;
    }
    acs[((size_t)((b * NH + h) * NCK + c)) * CH + t] = sc[t];
}

// ---- 4: Gb[t][s] = masked bf16( sum_n Cm[t,n]*Bm[s,n] ) per (b,c) ----
__global__ void g_kernel(const u16* __restrict__ xbc, u16* __restrict__ Gb) {
    int blk = blockIdx.x;
    int bc = blk >> 4;
    int tile = blk & 15;
    int tb0 = (tile >> 2) * 64, sb0 = (tile & 3) * 64;
    int row0 = bc * CH;
    __shared__ float Ct[64][65], Bt_[64][65];
    int tq = (threadIdx.x >> 4) * 4;
    int sq = (threadIdx.x & 15) * 4;
    float acc[4][4] = {};
    for (int nh = 0; nh < 2; nh++) {
        __syncthreads();
        int r = threadIdx.x >> 2, cc = (threadIdx.x & 3) * 16;
        for (int q = 0; q < 16; q += 4) {
            ushort4 cv = *(const ushort4*)&xbc[(size_t)(row0 + tb0 + r) * CDIM + (DI + DS) + nh * 64 + cc + q];
            ushort4 bv = *(const ushort4*)&xbc[(size_t)(row0 + sb0 + r) * CDIM + DI + nh * 64 + cc + q];
            Ct[r][cc + q] = bf2f(cv.x); Ct[r][cc + q + 1] = bf2f(cv.y); Ct[r][cc + q + 2] = bf2f(cv.z); Ct[r][cc + q + 3] = bf2f(cv.w);
            Bt_[r][cc + q] = bf2f(bv.x); Bt_[r][cc + q + 1] = bf2f(bv.y); Bt_[r][cc + q + 2] = bf2f(bv.z); Bt_[r][cc + q + 3] = bf2f(bv.w);
        }
        __syncthreads();
        for (int n = 0; n < 64; n++) {
            float a[4], bb[4];
            for (int i = 0; i < 4; i++) a[i] = Ct[tq + i][n];
            for (int j = 0; j < 4; j++) bb[j] = Bt_[sq + j][n];
            for (int i = 0; i < 4; i++)
                for (int j = 0; j < 4; j++) acc[i][j] += a[i] * bb[j];
        }
    }
    for (int i = 0; i < 4; i++)
        for (int j = 0; j < 4; j++) {
            int t = tb0 + tq + i, s = sb0 + sq + j;
            Gb[((size_t)(bc * CH + t)) * CH + s] = (s <= t) ? f2bf(acc[i][j]) : (u16)0;
        }
}

// ---- 4b: BmT[n][row] = xbc[row][DI+n]  (128 x 4096 bf16) ----
__global__ void bmt_kernel(const u16* __restrict__ xbc, u16* __restrict__ BmT) {
    __shared__ u16 tile[64 * 72];
    int n0 = blockIdx.x * 64, r0 = blockIdx.y * 64;
    int tid = threadIdx.x;
    {
        int r = tid >> 2, seg = (tid & 3) * 16;
        const u16* src = xbc + (size_t)(r0 + r) * CDIM + DI + n0 + seg;
        *(int4*)(tile + r * 72 + seg)     = *(const int4*)(src);
        *(int4*)(tile + r * 72 + seg + 8) = *(const int4*)(src + 8);
    }
    __syncthreads();
    {
        int n = tid >> 2, seg = (tid & 3) * 16;
        union { u16 v[16]; int4 q[2]; } o;
        for (int q = 0; q < 16; q++) o.v[q] = tile[(seg + q) * 72 + n];
        u16* dst = BmT + (size_t)(n0 + n) * MROWS + r0 + seg;
        *(int4*)(dst)     = o.q[0];
        *(int4*)(dst + 8) = o.q[1];
    }
}

// ---- 5: states[p][n] = sum_t (X[t,p]*dt[t]*decay[t]) * Bm[t,n]  per (b,c,h) — MFMA ----
__global__ __launch_bounds__(256) void states_kernel(const u16* __restrict__ xbc, const u16* __restrict__ BmT,
                                                     const float* __restrict__ dtbT, const float* __restrict__ acs_g,
                                                     float* __restrict__ states) {
    int bid = blockIdx.x;                 // (b,c,h)
    int h = bid & 63, c = (bid >> 6) & 7, b = bid >> 9;
    int row0 = b * L_SZ + c * CH;
    int tid = threadIdx.x;
    int lane = tid & 63, w = tid >> 6;
    int quad = lane >> 4, lm = lane & 15;
    int mh = (w >> 1) * 32, nh = (w & 1) * 64;

    __shared__ float wsc[CH];
    __shared__ u16 XTs[64 * 136];         // [p][t_local], pad 136

    {
        size_t abase = ((size_t)((b * NH + h) * NCK + c)) * CH;
        float a255 = acs_g[abase + 255];
        float at = acs_g[abase + tid];
        wsc[tid] = dtbT[(size_t)h * MROWS + row0 + tid] * expf(a255 - at);
    }
    f32x4 acc[2][4] = {};
    for (int k0 = 0; k0 < CH; k0 += 128) {
        __syncthreads();
        {   // stage scaled-transposed X chunk: thread -> (t row, 32 p)
            int tl = tid >> 1;            // 0..127
            int pseg = (tid & 1) * 32;
            float wv = wsc[k0 + tl];
            const u16* xr = xbc + (size_t)(row0 + k0 + tl) * CDIM + h * HD + pseg;
            for (int q4 = 0; q4 < 4; q4++) {
                bf16x8 v = *(const bf16x8*)(xr + q4 * 8);
                for (int e = 0; e < 8; e++)
                    XTs[(pseg + q4 * 8 + e) * 136 + tl] = f2bf(bf2f((u16)v[e]) * wv);
            }
        }
        __syncthreads();
        for (int ks = 0; ks < 4; ks++) {
            bf16x8 af[2];
            for (int i = 0; i < 2; i++)
                af[i] = *(const bf16x8*)(XTs + (mh + i * 16 + lm) * 136 + ks * 32 + quad * 8);
            for (int j = 0; j < 4; j++) {
                const u16* brow = BmT + (size_t)(nh + j * 16 + lm) * MROWS + row0 + k0 + ks * 32 + quad * 8;
                bf16x8 bfr = *(const bf16x8*)brow;
                for (int i = 0; i < 2; i++)
                    acc[i][j] = __builtin_amdgcn_mfma_f32_16x16x32_bf16(af[i], bfr, acc[i][j], 0, 0, 0);
            }
        }
    }
    float* st = states + (size_t)bid * (HD * DS);
    for (int i = 0; i < 2; i++)
        for (int j = 0; j < 4; j++)
            for (int r = 0; r < 4; r++) {
                int p = mh + i * 16 + quad * 4 + r;
                int n = nh + j * 16 + lm;
                st[p * DS + n] = acc[i][j][r];
            }
}

// ---- 6: inter-chunk scan IN PLACE ----
__global__ void cscan_kernel(float* __restrict__ states, const float* __restrict__ acs_g) {
    int bid = blockIdx.x;
    int h = bid & 63, b = bid >> 6;
    int tid = threadIdx.x;
    float4 carry[8];
    for (int i = 0; i < 8; i++) carry[i] = make_float4(0.f, 0.f, 0.f, 0.f);
    for (int c = 0; c < NCK; c++) {
        size_t base = ((size_t)((b * NCK + c) * NH + h)) * (HD * DS);
        float g = expf(acs_g[((size_t)((b * NH + h) * NCK + c)) * CH + (CH - 1)]);
        float4* sp = (float4*)(states + base);
        for (int i = 0; i < 8; i++) {
            int idx = tid + 256 * i;
            float4 s = sp[idx];
            sp[idx] = carry[i];
            carry[i].x = carry[i].x * g + s.x;
            carry[i].y = carry[i].y * g + s.y;
            carry[i].z = carry[i].z * g + s.z;
            carry[i].w = carry[i].w * g + s.w;
        }
    }
}

// ---- 7: y = Yo + Yd + D_skip*x per (b,c,h) — MFMA, register-built Yd A-frags ----
__global__ __launch_bounds__(256) void y_kernel(const u16* __restrict__ xbc, const float* __restrict__ dtbT,
                                                const float* __restrict__ acs_g, const u16* __restrict__ Gb,
                                                const float* __restrict__ init_st, const float* __restrict__ D_skip,
                                                u16* __restrict__ y) {
    int bid = blockIdx.x;                 // (b,c,h)
    int h = bid & 63, c = (bid >> 6) & 7, b = bid >> 9;
    int bc = b * NCK + c;
    int row0 = b * L_SZ + c * CH;
    int tid = threadIdx.x;
    int lane = tid & 63, w = tid >> 6;
    int wt = w * 64;
    int quad = lane >> 4, lm = lane & 15;

    __shared__ float acs[CH];             // 1 KB
    __shared__ u16 Ssb[64 * 136];         // 17.4 KB  states bf16 [p][n] pad 136
    __shared__ u16 XT[64 * 72];           // 9.2 KB   Xdt^T [p][s_local] pad 72

    acs[tid] = acs_g[((size_t)((b * NH + h) * NCK + c)) * CH + tid];
    {   // init_st f32 [p][n] -> bf16 LDS padded
        const float4* sg = (const float4*)(init_st + ((size_t)(bc * NH + h)) * (HD * DS));
        for (int i = 0; i < 8; i++) {
            int g = tid + 256 * i;
            int p = g >> 5, n4 = (g & 31) * 4;
            float4 v = sg[g];
            ushort4 o;
            o.x = f2bf(v.x); o.y = f2bf(v.y); o.z = f2bf(v.z); o.w = f2bf(v.w);
            *(ushort4*)(Ssb + p * 136 + n4) = o;
        }
    }
    __syncthreads();

    f32x4 acc[4][4] = {};
    // ---- Yo: A = raw Cm rows from global; B = Ssb ----
    for (int i = 0; i < 4; i++) {
        const u16* arow = xbc + (size_t)(row0 + wt + i * 16 + lm) * CDIM + (DI + DS);
        for (int ks = 0; ks < 4; ks++) {
            bf16x8 af = *(const bf16x8*)(arow + ks * 32 + quad * 8);
            for (int j = 0; j < 4; j++) {
                bf16x8 bfr = *(const bf16x8*)(Ssb + (j * 16 + lm) * 136 + ks * 32 + quad * 8);
                acc[i][j] = __builtin_amdgcn_mfma_f32_16x16x32_bf16(af, bfr, acc[i][j], 0, 0, 0);
            }
        }
    }
    for (int i = 0; i < 4; i++) {
        float et[4];
        for (int r = 0; r < 4; r++) et[r] = expf(acs[wt + i * 16 + quad * 4 + r]);
        for (int j = 0; j < 4; j++)
            for (int r = 0; r < 4; r++) acc[i][j][r] *= et[r];
    }

    // ---- Yd: A-frag built in registers from masked Gb + exp; B = XT (dt folded) ----
    const u16* gball = Gb + (size_t)bc * CH * CH;
    for (int s0 = 0; s0 < CH; s0 += 64) {
        __syncthreads();
        {   // XT[p][s_local] = x[s][p] * dt[s]
            int r = tid >> 2, cseg = (tid & 3) * 16;
            int row = row0 + s0 + r;
            float dv = dtbT[(size_t)h * MROWS + row];
            const u16* xr = xbc + (size_t)row * CDIM + h * HD + cseg;
            for (int q8 = 0; q8 < 2; q8++) {
                bf16x8 v = *(const bf16x8*)(xr + q8 * 8);
                for (int e = 0; e < 8; e++)
                    XT[(cseg + q8 * 8 + e) * 72 + r] = f2bf(bf2f((u16)v[e]) * dv);
            }
        }
        __syncthreads();
        if (wt + 63 < s0) continue;
        for (int i = 0; i < 4; i++) {
            int tTop = wt + i * 16 + 15;
            if (tTop < s0) continue;
            int t = wt + i * 16 + lm;
            float at = acs[t];
            const u16* grow_ = gball + (size_t)t * CH + s0;
            for (int ks = 0; ks < 2; ks++) {
                if (s0 + ks * 32 > tTop) continue;
                bf16x8 g8 = *(const bf16x8*)(grow_ + ks * 32 + quad * 8);
                const float* asp = &acs[s0 + ks * 32 + quad * 8];
                bf16x8 af;
                for (int e = 0; e < 8; e++) {
                    float m = bf2f((u16)g8[e]) * expf(fminf(at - asp[e], 0.f));
                    af[e] = (short)f2bf(m);
                }
                for (int j = 0; j < 4; j++) {
                    bf16x8 bfr = *(const bf16x8*)(XT + (j * 16 + lm) * 72 + ks * 32 + quad * 8);
                    acc[i][j] = __builtin_amdgcn_mfma_f32_16x16x32_bf16(af, bfr, acc[i][j], 0, 0, 0);
                }
            }
        }
    }

    // ---- epilogue ----
    float dsk = D_skip[h];
    for (int i = 0; i < 4; i++)
        for (int r = 0; r < 4; r++) {
            int grow = row0 + wt + i * 16 + quad * 4 + r;
            const u16* xrow = xbc + (size_t)grow * CDIM + h * HD;
            u16* yrow = y + (size_t)grow * DI + h * HD;
            for (int j = 0; j < 4; j++) {
                int p = j * 16 + lm;
                yrow[p] = f2bf(acc[i][j][r] + dsk * bf2f(xrow[p]));
            }
        }
}

// ---- 8: out = (y * silu(z)) * rsqrt(mean(yg^2)+eps) * norm_w ----
__global__ void final_kernel(const u16* __restrict__ y, const u16* __restrict__ zx,
                             const float* __restrict__ norm_w, float* __restrict__ out) {
    int row = blockIdx.x;
    int tid = threadIdx.x;
    __shared__ float red[4];
    float yg[16];
    float ss = 0.f;
    for (int i = 0; i < 16; i++) {
        int col = tid + 256 * i;
        float z = bf2f(zx[(size_t)row * NP + col]);
        float g = bf2f(y[(size_t)row * DI + col]) * (z / (1.f + expf(-z)));
        yg[i] = g; ss += g * g;
    }
    for (int off = 32; off; off >>= 1) ss += __shfl_down(ss, off);
    if ((tid & 63) == 0) red[tid >> 6] = ss;
    __syncthreads();
    if (tid == 0) red[0] = red[0] + red[1] + red[2] + red[3];
    __syncthreads();
    float inv = rsqrtf(red[0] / (float)DI + 1e-5f);
    for (int i = 0; i < 16; i++) {
        int col = tid + 256 * i;
        out[(size_t)row * DI + col] = yg[i] * inv * norm_w[col];
    }
}

extern "C" void kernel_launch(void* const* d_in, const int* in_sizes, int n_in,
                              void* d_out, int out_size, void* d_ws, size_t ws_size,
                              hipStream_t stream) {
    const float* u       = (const float*)d_in[0];
    const float* w_in    = (const float*)d_in[1];
    const float* conv_w  = (const float*)d_in[2];
    const float* conv_b  = (const float*)d_in[3];
    const float* dt_bias = (const float*)d_in[4];
    const float* A_log   = (const float*)d_in[5];
    const float* D_skip  = (const float*)d_in[6];
    const float* norm_w  = (const float*)d_in[7];
    float* out = (float*)d_out;

    const size_t NEEDED = 179306496ull;   // layout unchanged from round 4
    if (ws_size < NEEDED) return;

    char* ws = (char*)d_ws;
    const size_t R = 70254592ull;
    u16*   zx   = (u16*)ws;                         // 70,254,592
    u16*   ubf  = (u16*)(ws + R);                   // GEMM phase
    u16*   wtb  = (u16*)(ws + R + 16777216);        // GEMM phase
    u16*   xbc  = (u16*)(ws + R);                   // post-GEMM, 35,651,584
    float* dtbT = (float*)(ws + R + 35651584);      // 1 MB  [h][row]
    float* acs  = (float*)(ws + R + 36700160);      // 1 MB
    u16*   Gb   = (u16*)(ws + R + 37748736);        // 2 MB  masked bf16
    u16*   BmT  = (u16*)(ws + R + 39845888);        // 1 MB  [n][row]
    float* stat = (float*)(ws + R + 41943040);      // 33.5 MB
    u16*   yb   = (u16*)(ws + R + 75497472);        // 33.5 MB

    cvt_u_kernel<<<8192, 256, 0, stream>>>(u, ubf);
    transpose_w_kernel<<<dim3(268, 64), 256, 0, stream>>>(w_in, wtb);
    gemm_kernel<<<GEMM_NM * GEMM_NN, 256, 0, stream>>>(ubf, wtb, zx);
    conv_silu_kernel<<<dim3(17, 4096), 256, 0, stream>>>(zx, conv_w, conv_b, xbc);
    dt_scan_kernel<<<1024, 256, 0, stream>>>(zx, dt_bias, A_log, dtbT, acs);
    g_kernel<<<256, 256, 0, stream>>>(xbc, Gb);
    bmt_kernel<<<dim3(2, 64), 256, 0, stream>>>(xbc, BmT);
    states_kernel<<<1024, 256, 0, stream>>>(xbc, BmT, dtbT, acs, stat);
    cscan_kernel<<<128, 256, 0, stream>>>(stat, acs);
    y_kernel<<<1024, 256, 0, stream>>>(xbc, dtbT, acs, Gb, stat, D_skip, yb);
    final_kernel<<<4096, 256, 0, stream>>>(yb, zx, norm_w, out);
}